// Round 12
// baseline (240.109 us; speedup 1.0000x reference)
//
#include <hip/hip_runtime.h>
#include <hip/hip_bf16.h>

// Problem constants
#define B_    4
#define C_    192
#define C2_   384
#define PIX_  16384      // 128*128
#define NH_   6
#define BG_   1024
#define SCALE_ 0.17677669529663687f   // 32^-0.5
// exp(s*SCALE - SCALE) == exp2(fmaf(s, C1, -C1)), C1 = SCALE*log2(e).
// Valid because |s|<=1 (cosine of unit vectors) -> constant max M=1 is safe.
#define C1_ 0.2550348943f

typedef __attribute__((ext_vector_type(8))) short short8v;   // 8 bf16 = 4 VGPR
typedef __attribute__((ext_vector_type(4))) float f32x4;

// v_cvt_pk_bf16_f32: packs 2 f32 -> 2 bf16 (RNE) in one instruction.
__device__ __forceinline__ unsigned cvt_pk_bf16(float lo, float hi) {
    unsigned r;
    asm("v_cvt_pk_bf16_f32 %0, %1, %2" : "=v"(r) : "v"(lo), "v"(hi));
    return r;
}

// ---------------------------------------------------------------------------
// Kernel 0: RoPE cos/sin table
// ---------------------------------------------------------------------------
__global__ __launch_bounds__(256, 1)
void k_rope_init(float2* __restrict__ tbl) {
    int e = blockIdx.x * 256 + threadIdx.x;    // 4096 entries
    if (e >= 4096) return;
    int pos = e >> 4, j = e & 15;
    float freq = powf(10.0f, -0.25f * (float)j);
    float ang = (float)pos * freq;
    float sn, cs;
    sincosf(ang, &sn, &cs);
    tbl[e] = make_float2(cs, sn);
}

// ---------------------------------------------------------------------------
// Kernel 0b: graph int32 -> bitmask
// ---------------------------------------------------------------------------
__global__ __launch_bounds__(256, 4)
void k_gmask(const int* __restrict__ g, unsigned int* __restrict__ gbits) {
    int e = blockIdx.x * 256 + threadIdx.x;            // 524288 dwords
    const uint4* p = (const uint4*)(g + (size_t)e * 32);
    unsigned int m = 0u;
#pragma unroll
    for (int i = 0; i < 8; ++i) {
        uint4 v = p[i];
        m |= (v.x ? 1u : 0u) << (i * 4);
        m |= (v.y ? 1u : 0u) << (i * 4 + 1);
        m |= (v.z ? 1u : 0u) << (i * 4 + 2);
        m |= (v.w ? 1u : 0u) << (i * 4 + 3);
    }
    gbits[e] = m;
}

// ---------------------------------------------------------------------------
// Kernel 0c: cast w_sample ++ w_group ++ w_proj -> bf16
// ---------------------------------------------------------------------------
__global__ __launch_bounds__(256, 4)
void k_wcast(const float* __restrict__ wsm, const float* __restrict__ wgb,
             const float* __restrict__ wpj, __hip_bfloat16* __restrict__ wb)
{
    int e = (blockIdx.x * 256 + threadIdx.x) * 4;      // 147456 elems
    float4 v = (e < 73728) ? *(const float4*)(wsm + e)
             : (e < 110592) ? *(const float4*)(wgb + (e - 73728))
                            : *(const float4*)(wpj + (e - 110592));
    uint2 pk = make_uint2(cvt_pk_bf16(v.x, v.y), cvt_pk_bf16(v.z, v.w));
    *(uint2*)(wb + e) = pk;
}

// ---------------------------------------------------------------------------
// Kernel 1 (MFMA): fused 1x1 conv 192 -> 576, one block per 32-px tile,
// ONE barrier. Grid 2048 -> 8 blocks/CU = 8 waves/SIMD (2x round-11 TLP).
// Wave quadrant: 16 px (pb2) x 32 oc (ob2); 6 hoisted x-frags (24 VGPR),
// launch_bounds(256,8) caps VGPR at 64 so the hoist + 8 waves/SIMD hold.
// V octs: A=x,B=w -> D[px][oc], direct channel-major stores.
// K/Q octs: A=w,B=x -> D[oc][px]; per-lane single pixel -> in-reg bias/
// RoPE/norm (2 shfl_xor) and packed token-major stores. No LDS epilogues.
// ---------------------------------------------------------------------------
__global__ __launch_bounds__(256, 8)
void k_convm(const float* __restrict__ x, const __hip_bfloat16* __restrict__ wb,
             const float* __restrict__ bsm, const float* __restrict__ bgb,
             const float2* __restrict__ tbl,
             __hip_bfloat16* __restrict__ xsk, __hip_bfloat16* __restrict__ xsv,
             __hip_bfloat16* __restrict__ qbf)
{
    __shared__ __align__(16) char smem[12800];   // xt [32px][400B]
    const int bid0 = blockIdx.x;
    const int bid = (bid0 & 7) * 256 + (bid0 >> 3);   // 2048 = 8 x 256, bijective
    const int b = bid >> 9, pt = bid & 511;
    const int px0 = pt * 32;
    const int t = threadIdx.x;

    // ---- stage x tile [32 px][192 c] -> bf16 LDS, transposed (once) ----
    {
        const int px = t & 31, cq = t >> 5;           // cq: 8 groups x 24 ch
        const float* src = x + ((size_t)b * C_ + cq * 24) * PIX_ + px0 + px;
        char* row = smem + px * 400 + cq * 48;
#pragma unroll
        for (int i = 0; i < 3; ++i) {
            float f[8];
#pragma unroll
            for (int j = 0; j < 8; ++j) f[j] = src[(size_t)(i * 8 + j) * PIX_];
            uint4 pk4;
            pk4.x = cvt_pk_bf16(f[0], f[1]); pk4.y = cvt_pk_bf16(f[2], f[3]);
            pk4.z = cvt_pk_bf16(f[4], f[5]); pk4.w = cvt_pk_bf16(f[6], f[7]);
            *(uint4*)(row + i * 16) = pk4;
        }
    }
    __syncthreads();   // the ONLY barrier

    const int w = t >> 6, lane = t & 63;
    const int l15 = lane & 15, g = lane >> 4;
    const int pb2 = (w & 1) * 16;    // px half
    const int ob2 = (w >> 1) * 32;   // oc half

    // ---- hoist x-frags (rows pb2+l15): 6 frags = 24 VGPR ----
    short8v xf[6];
#pragma unroll
    for (int ks = 0; ks < 6; ++ks)
        xf[ks] = *(const short8v*)(smem + (pb2 + l15) * 400 + ks * 64 + g * 16);

    const f32x4 zz = {0.0f, 0.0f, 0.0f, 0.0f};

    // ================= V octs: A=x, B=w; direct store =====================
#pragma unroll
    for (int o2 = 0; o2 < 3; ++o2) {
        const int oct = 3 + o2;
        f32x4 acc0 = zz, acc1 = zz;
        const __hip_bfloat16* w0 = wb + (size_t)(oct * 64 + ob2 + l15) * C_;
        const __hip_bfloat16* w1 = w0 + 16 * C_;
#pragma unroll
        for (int ks = 0; ks < 6; ++ks) {
            const short8v b0 = *(const short8v*)(w0 + ks * 32 + g * 8);
            const short8v b1 = *(const short8v*)(w1 + ks * 32 + g * 8);
            acc0 = __builtin_amdgcn_mfma_f32_16x16x32_bf16(xf[ks], b0, acc0, 0, 0, 0);
            acc1 = __builtin_amdgcn_mfma_f32_16x16x32_bf16(xf[ks], b1, acc1, 0, 0, 0);
        }
        // acc0: (px = pb2 + 4g + j, oc = ob2 + l15); acc1: oc + 16
        const float bo0 = bsm[oct * 64 + ob2 + l15];
        const float bo1 = bsm[oct * 64 + ob2 + 16 + l15];
        uint2 p0 = make_uint2(cvt_pk_bf16(acc0[0] + bo0, acc0[1] + bo0),
                              cvt_pk_bf16(acc0[2] + bo0, acc0[3] + bo0));
        uint2 p1 = make_uint2(cvt_pk_bf16(acc1[0] + bo1, acc1[1] + bo1),
                              cvt_pk_bf16(acc1[2] + bo1, acc1[3] + bo1));
        __hip_bfloat16* d0 = xsv + (size_t)(b * C_ + o2 * 64 + ob2 + l15) * PIX_
                                 + px0 + pb2 + g * 4;
        *(uint2*)d0 = p0;
        *(uint2*)(d0 + (size_t)16 * PIX_) = p1;        // oc + 16
    }

    // ================= K octs: A=w, B=x -> D[oc][px]; in-reg norm =========
    // a0: (oc = ob2 + 4g + j, px = pb2 + l15); a1: oc + 16. One head/wave/oct.
#pragma unroll
    for (int o2 = 0; o2 < 3; ++o2) {
        const int oct = o2;
        f32x4 a0 = zz, a1 = zz;
        const __hip_bfloat16* w0 = wb + (size_t)(oct * 64 + ob2 + l15) * C_;
        const __hip_bfloat16* w1 = w0 + 16 * C_;
#pragma unroll
        for (int ks = 0; ks < 6; ++ks) {
            const short8v wf0 = *(const short8v*)(w0 + ks * 32 + g * 8);
            const short8v wf1 = *(const short8v*)(w1 + ks * 32 + g * 8);
            a0 = __builtin_amdgcn_mfma_f32_16x16x32_bf16(wf0, xf[ks], a0, 0, 0, 0);
            a1 = __builtin_amdgcn_mfma_f32_16x16x32_bf16(wf1, xf[ks], a1, 0, 0, 0);
        }
        const float4 bv0 = *(const float4*)(bsm + oct * 64 + ob2 + g * 4);
        const float4 bv1 = *(const float4*)(bsm + oct * 64 + ob2 + 16 + g * 4);
        a0[0] += bv0.x; a0[1] += bv0.y; a0[2] += bv0.z; a0[3] += bv0.w;
        a1[0] += bv1.x; a1[1] += bv1.y; a1[2] += bv1.z; a1[3] += bv1.w;
        float s = 0.0f;
#pragma unroll
        for (int j = 0; j < 4; ++j) {
            s = fmaf(a0[j], a0[j], s);
            s = fmaf(a1[j], a1[j], s);
        }
        s += __shfl_xor(s, 16); s += __shfl_xor(s, 32);
        const float inv = 1.0f / fmaxf(sqrtf(s), 1e-12f);
        uint2 q0 = make_uint2(cvt_pk_bf16(a0[0] * inv, a0[1] * inv),
                              cvt_pk_bf16(a0[2] * inv, a0[3] * inv));
        uint2 q1 = make_uint2(cvt_pk_bf16(a1[0] * inv, a1[1] * inv),
                              cvt_pk_bf16(a1[2] * inv, a1[3] * inv));
        __hip_bfloat16* d = xsk + ((size_t)b * PIX_ + px0 + pb2 + l15) * C_
                                + oct * 64 + ob2 + g * 4;
        *(uint2*)d        = q0;
        *(uint2*)(d + 16) = q1;                        // oc + 16
    }

    // ================= Q octs: A=w, B=x; in-reg RoPE + norm ================
    // Per-lane single pixel p -> single (n, bg).
    const int p  = px0 + pb2 + l15;
    const int r  = p >> 7, c = p & 127;
    const int n  = (r & 7) * 8 + (c & 7);
    const int bg = (b << 8) + ((r >> 3) << 4) + (c >> 3);
#pragma unroll
    for (int o2 = 0; o2 < 3; ++o2) {
        const int oct = 6 + o2;
        f32x4 a0 = zz, a1 = zz;
        const __hip_bfloat16* w0 = wb + (size_t)(oct * 64 + ob2 + l15) * C_;
        const __hip_bfloat16* w1 = w0 + 16 * C_;
#pragma unroll
        for (int ks = 0; ks < 6; ++ks) {
            const short8v wf0 = *(const short8v*)(w0 + ks * 32 + g * 8);
            const short8v wf1 = *(const short8v*)(w1 + ks * 32 + g * 8);
            a0 = __builtin_amdgcn_mfma_f32_16x16x32_bf16(wf0, xf[ks], a0, 0, 0, 0);
            a1 = __builtin_amdgcn_mfma_f32_16x16x32_bf16(wf1, xf[ks], a1, 0, 0, 0);
        }
        const float4 bv0 = *(const float4*)(bgb + (oct - 6) * 64 + ob2 + g * 4);
        const float4 bv1 = *(const float4*)(bgb + (oct - 6) * 64 + ob2 + 16 + g * 4);
        a0[0] += bv0.x; a0[1] += bv0.y; a0[2] += bv0.z; a0[3] += bv0.w;
        a1[0] += bv1.x; a1[1] += bv1.y; a1[2] += bv1.z; a1[3] += bv1.w;
        // RoPE: a0 = head-rel ch 4g+j -> pairs 2g, 2g+1; a1 -> pairs 8+2g, 8+2g+1
        {
            float2 cA = tbl[n * 16 + 2 * g], cB = tbl[n * 16 + 2 * g + 1];
            { float u0 = a0[0], u1 = a0[1];
              a0[0] = u0 * cA.x - u1 * cA.y; a0[1] = u1 * cA.x + u0 * cA.y; }
            { float u0 = a0[2], u1 = a0[3];
              a0[2] = u0 * cB.x - u1 * cB.y; a0[3] = u1 * cB.x + u0 * cB.y; }
            cA = tbl[n * 16 + 8 + 2 * g]; cB = tbl[n * 16 + 8 + 2 * g + 1];
            { float u0 = a1[0], u1 = a1[1];
              a1[0] = u0 * cA.x - u1 * cA.y; a1[1] = u1 * cA.x + u0 * cA.y; }
            { float u0 = a1[2], u1 = a1[3];
              a1[2] = u0 * cB.x - u1 * cB.y; a1[3] = u1 * cB.x + u0 * cB.y; }
        }
        float s = 0.0f;
#pragma unroll
        for (int j = 0; j < 4; ++j) {
            s = fmaf(a0[j], a0[j], s);
            s = fmaf(a1[j], a1[j], s);
        }
        s += __shfl_xor(s, 16); s += __shfl_xor(s, 32);
        const float inv = 1.0f / fmaxf(sqrtf(s), 1e-12f);
        uint2 q0 = make_uint2(cvt_pk_bf16(a0[0] * inv, a0[1] * inv),
                              cvt_pk_bf16(a0[2] * inv, a0[3] * inv));
        uint2 q1 = make_uint2(cvt_pk_bf16(a1[0] * inv, a1[1] * inv),
                              cvt_pk_bf16(a1[2] * inv, a1[3] * inv));
        const int hglob = (oct - 6) * 2 + (ob2 >> 5);
        __hip_bfloat16* d = qbf + (((size_t)bg * NH_ + hglob) * 64 + n) * 32 + g * 4;
        *(uint2*)d        = q0;
        *(uint2*)(d + 16) = q1;                        // ch + 16
    }
}

// ---------------------------------------------------------------------------
// Kernel 3 (MFMA): attention for one (bg, head).  (round-11 structure)
// ---------------------------------------------------------------------------
__global__ __launch_bounds__(512, 2)
void k_attn(const __hip_bfloat16* __restrict__ xsk, const __hip_bfloat16* __restrict__ xsv,
            const unsigned int* __restrict__ gbits, const __hip_bfloat16* __restrict__ qb,
            const float2* __restrict__ tbl, float* __restrict__ attn)
{
    __shared__ __align__(16) char smem[52736];
    const int bid0 = blockIdx.x;
    const int bid = (bid0 & 7) * 768 + (bid0 >> 3);    // 6144 = 8 x 768, bijective
    const int h = bid % NH_;
    const int bg = bid / NH_;
    const int b = bg >> 8, ph = (bg >> 4) & 15, pw = bg & 15;
    const int t = threadIdx.x;
    const int w = t >> 6, lane = t & 63;
    const int g = lane >> 4, l15 = lane & 15;
    const int rbase = (w & 3) * 16;        // q rows
    const int wcol  = w >> 2;              // kv half
    const int cb    = wcol * 128;
    const int cb32  = wcol * 4;

    // ---- B-frag: Q direct from global (issue early) ----
    const short8v qa = *(const short8v*)(qb +
        ((size_t)(bg * NH_ + h) * 64 + rbase + l15) * 32 + g * 8);

    // ---- stage K (rope only, pre-normalized) into kl: thread=(m,half) ----
    {
        const int m = t >> 1, half = t & 1;
        const int k0 = m >> 4, k1 = m & 15;
        const int rr = ph * 8 - 4 + k0, cc = pw * 8 - 4 + k1;
        const bool inb = ((unsigned)rr < 128u) && ((unsigned)cc < 128u);
        float kv[16];
        if (inb) {
            const uint4* pk = (const uint4*)(xsk +
                ((size_t)b * PIX_ + rr * 128 + cc) * C_ + h * 32 + half * 16);
            union { uint4 u; __hip_bfloat16 h8[8]; } r0, r1;
            r0.u = pk[0]; r1.u = pk[1];
#pragma unroll
            for (int d = 0; d < 8; ++d) {
                kv[d]     = __bfloat162float(r0.h8[d]);
                kv[8 + d] = __bfloat162float(r1.h8[d]);
            }
        } else {
#pragma unroll
            for (int d = 0; d < 16; ++d) kv[d] = 0.0f;
        }
        unsigned pk8[8];
#pragma unroll
        for (int p = 0; p < 8; ++p) {
            float2 cs = tbl[m * 16 + half * 8 + p];
            float a0 = kv[2 * p], a1 = kv[2 * p + 1];
            float e0 = a0 * cs.x - a1 * cs.y;
            float e1 = a1 * cs.x + a0 * cs.y;
            pk8[p] = cvt_pk_bf16(e0, e1);
        }
        *(uint4*)(smem + m * 80 + half * 32)      = make_uint4(pk8[0], pk8[1], pk8[2], pk8[3]);
        *(uint4*)(smem + m * 80 + half * 32 + 16) = make_uint4(pk8[4], pk8[5], pk8[6], pk8[7]);
    }

    // ---- stage V transposed into vl[d][kv] (528B rows) ----
    {
        const int d = t & 31, k0 = t >> 5;
        const int rr = ph * 8 - 4 + k0;
        const int c0 = pw * 8 - 4;
        char* dst = smem + 34816 + d * 528 + k0 * 32;
        const __hip_bfloat16* src = xsv + (size_t)(b * C_ + h * 32 + d) * PIX_ + rr * 128 + c0;
        const bool rok = (unsigned)rr < 128u;
        if (rok && pw >= 1 && pw <= 14) {
            const uint2* s2 = (const uint2*)src;   // 8B aligned
            uint2 a0 = s2[0], a1 = s2[1], a2 = s2[2], a3 = s2[3];
            ((uint4*)dst)[0] = make_uint4(a0.x, a0.y, a1.x, a1.y);
            ((uint4*)dst)[1] = make_uint4(a2.x, a2.y, a3.x, a3.y);
        } else {
            __hip_bfloat16* dh = (__hip_bfloat16*)dst;
            __hip_bfloat16 z = __float2bfloat16(0.0f);
#pragma unroll
            for (int i = 0; i < 16; ++i) {
                bool ok = rok && ((unsigned)(c0 + i) < 128u);
                dh[i] = ok ? src[i] : z;
            }
        }
    }

    // ---- stage graph bits: gb[q][9] uints ----
    {
        unsigned int* gbl = (unsigned int*)(smem + 20480);
        const int q = t >> 3, wd = t & 7;
        gbl[q * 9 + wd] = gbits[(size_t)bg * 512 + t];
    }
    __syncthreads();   // sync1

    // ---- sim = K Q^T (swapped): D[kt][q], lane: q = rbase+l15, kt = tile*16+4g+j
    f32x4 acc[8];
    const f32x4 zz = {0.0f, 0.0f, 0.0f, 0.0f};
#pragma unroll
    for (int tile = 0; tile < 8; ++tile) {
        const short8v kb = *(const short8v*)(smem + (cb + tile * 16 + l15) * 80 + g * 16);
        acc[tile] = __builtin_amdgcn_mfma_f32_16x16x32_bf16(kb, qa, zz, 0, 0, 0);
    }

    // ---- masked exp (constant max) + row sum (per-lane single q) ----
    const unsigned int* gbl = (const unsigned int*)(smem + 20480);
    float* reds = (float*)(smem + 51712);   // [64 q][2 wcol]
    {
        const int q = rbase + l15;
        const unsigned int wv[4] = { gbl[q * 9 + cb32], gbl[q * 9 + cb32 + 1],
                                     gbl[q * 9 + cb32 + 2], gbl[q * 9 + cb32 + 3] };
        float sm = 0.0f;
#pragma unroll
        for (int tile = 0; tile < 8; ++tile) {
            const unsigned int bits = wv[tile >> 1] >> ((tile & 1) * 16 + (g << 2));
#pragma unroll
            for (int j = 0; j < 4; ++j) {
                float e = __builtin_amdgcn_exp2f(fmaf(acc[tile][j], C1_, -C1_));
                e = ((bits >> j) & 1u) ? e : 0.0f;
                acc[tile][j] = e;
                sm += e;
            }
        }
        sm += __shfl_xor(sm, 16);
        sm += __shfl_xor(sm, 32);
        if (lane < 16) reds[q * 2 + wcol] = sm;
    }
    __syncthreads();   // sync2 (sum exchange; also: all QK kl reads done)

    float inv4[4];
#pragma unroll
    for (int j = 0; j < 4; ++j) {
        const int qq = rbase + (g << 2) + j;
        float2 rr2 = *(const float2*)&reds[qq * 2];
        inv4[j] = 1.0f / (rr2.x + rr2.y + 1e-37f);
    }

    // ---- write P (bf16, UNNORMALIZED): 8B per tile per lane ----
    char* plw = smem + w * 4352;   // [16 q][272B]
#pragma unroll
    for (int tile = 0; tile < 8; ++tile) {
        uint2 pw2 = make_uint2(cvt_pk_bf16(acc[tile][0], acc[tile][1]),
                               cvt_pk_bf16(acc[tile][2], acc[tile][3]));
        *(uint2*)(plw + l15 * 272 + tile * 32 + g * 8) = pw2;
    }

    // ---- PV ----
    f32x4 o0 = zz, o1 = zz;
#pragma unroll
    for (int ks = 0; ks < 4; ++ks) {
        const short8v pa  = *(const short8v*)(plw + l15 * 272 + (ks * 32 + g * 8) * 2);
        const short8v vb0 = *(const short8v*)(smem + 34816 + l15 * 528        + (cb + ks * 32 + g * 8) * 2);
        const short8v vb1 = *(const short8v*)(smem + 34816 + (16 + l15) * 528 + (cb + ks * 32 + g * 8) * 2);
        o0 = __builtin_amdgcn_mfma_f32_16x16x32_bf16(pa, vb0, o0, 0, 0, 0);
        o1 = __builtin_amdgcn_mfma_f32_16x16x32_bf16(pa, vb1, o1, 0, 0, 0);
    }
    __syncthreads();   // sync3

    // ---- cross-half reduce + normalize-on-output + store ----
    float* ob = (float*)smem;   // [64][33] f32
    if (wcol == 1) {
#pragma unroll
        for (int j = 0; j < 4; ++j) {
            const int q = rbase + g * 4 + j;
            ob[q * 33 + l15]      = o0[j];
            ob[q * 33 + 16 + l15] = o1[j];
        }
    }
    __syncthreads();   // sync4
    if (wcol == 0) {
#pragma unroll
        for (int j = 0; j < 4; ++j) {
            const int q = rbase + g * 4 + j;
            float v0 = (o0[j] + ob[q * 33 + l15])      * inv4[j];
            float v1 = (o1[j] + ob[q * 33 + 16 + l15]) * inv4[j];
            attn[((size_t)bg * 64 + q) * 192 + h * 32 + l15]      = v0;
            attn[((size_t)bg * 64 + q) * 192 + h * 32 + 16 + l15] = v1;
        }
    }
}

// ---------------------------------------------------------------------------
// Kernel 4 (MFMA): final projection out = attn @ wp^T + bp, in-place on d_out.
// ---------------------------------------------------------------------------
__global__ __launch_bounds__(256, 4)
void k_oprojm(const float* __restrict__ attn, const __hip_bfloat16* __restrict__ wpb,
              const float* __restrict__ bp, float* __restrict__ out)
{
    __shared__ __align__(16) char smem[25600];   // at [64r][400B] bf16 / ot f32 [64px][68]
    const int bid0 = blockIdx.x;
    const int bid = (bid0 & 7) * 384 + (bid0 >> 3);   // 3072 = 8 x 384, bijective
    const int oct = bid % 3;
    const int rt  = bid / 3;
    const int row0 = rt * 64;
    const int t = threadIdx.x;

    // ---- stage A: attn[row0..+64][192] f32 -> bf16 LDS (coalesced) ----
#pragma unroll
    for (int e0 = 0; e0 < 12; ++e0) {
        const int e = e0 * 256 + t;          // 3072 float4s
        const int r = e / 48, c4 = e % 48;
        float4 v = *(const float4*)(attn + (size_t)(row0 + r) * 192 + c4 * 4);
        uint2 pk = make_uint2(cvt_pk_bf16(v.x, v.y), cvt_pk_bf16(v.z, v.w));
        *(uint2*)(smem + r * 400 + c4 * 8) = pk;
    }
    __syncthreads();

    const int w = t >> 6, lane = t & 63;
    const int l15 = lane & 15, g = lane >> 4;
    const int mb = (w & 1) * 32;     // row quadrant
    const int nb = (w >> 1) * 32;    // oc quadrant

    const f32x4 zz = {0.0f, 0.0f, 0.0f, 0.0f};
    f32x4 acc00 = zz, acc01 = zz, acc10 = zz, acc11 = zz;
    const __hip_bfloat16* w0 = wpb + (size_t)(oct * 64 + nb + l15) * C_;
    const __hip_bfloat16* w1 = w0 + 16 * C_;
#pragma unroll
    for (int ks = 0; ks < 6; ++ks) {
        const short8v a0 = *(const short8v*)(smem + (mb + l15) * 400      + ks * 64 + g * 16);
        const short8v a1 = *(const short8v*)(smem + (mb + 16 + l15) * 400 + ks * 64 + g * 16);
        const short8v b0 = *(const short8v*)(w0 + ks * 32 + g * 8);
        const short8v b1 = *(const short8v*)(w1 + ks * 32 + g * 8);
        acc00 = __builtin_amdgcn_mfma_f32_16x16x32_bf16(a0, b0, acc00, 0, 0, 0);
        acc01 = __builtin_amdgcn_mfma_f32_16x16x32_bf16(a0, b1, acc01, 0, 0, 0);
        acc10 = __builtin_amdgcn_mfma_f32_16x16x32_bf16(a1, b0, acc10, 0, 0, 0);
        acc11 = __builtin_amdgcn_mfma_f32_16x16x32_bf16(a1, b1, acc11, 0, 0, 0);
    }
    __syncthreads();   // A-frag reads done -> overlay ot

    // ---- store transposed ot[px][oc] (68-float rows) ----
    float* ot = (float*)smem;
#pragma unroll
    for (int j = 0; j < 4; ++j) {
        ot[(mb + g * 4 + j) * 68      + nb + l15]      = acc00[j];
        ot[(mb + 16 + g * 4 + j) * 68 + nb + l15]      = acc10[j];
        ot[(mb + g * 4 + j) * 68      + nb + 16 + l15] = acc01[j];
        ot[(mb + 16 + g * 4 + j) * 68 + nb + 16 + l15] = acc11[j];
    }
    __syncthreads();

    // ---- epilogue: bias + coalesced f32 write ----
    {
        const int k = t & 15, pxi = t >> 4;
        const float4 bias4 = *(const float4*)(bp + oct * 64 + k * 4);
#pragma unroll
        for (int p = 0; p < 4; ++p) {
            const int px = p * 16 + pxi;
            float4 v = *(const float4*)&ot[px * 68 + k * 4];
            v.x += bias4.x; v.y += bias4.y; v.z += bias4.z; v.w += bias4.w;
            *(float4*)(out + (size_t)(row0 + px) * 192 + oct * 64 + k * 4) = v;
        }
    }
}

// ---------------------------------------------------------------------------
extern "C" void kernel_launch(void* const* d_in, const int* in_sizes, int n_in,
                              void* d_out, int out_size, void* d_ws, size_t ws_size,
                              hipStream_t stream)
{
    (void)in_sizes; (void)n_in; (void)out_size; (void)ws_size;
    const float* x   = (const float*)d_in[0];
    const int* grph  = (const int*)d_in[1];     // jnp bool -> int32 per harness
    const float* wg  = (const float*)d_in[2];
    const float* bgb = (const float*)d_in[3];
    const float* wsm = (const float*)d_in[4];
    const float* bsm = (const float*)d_in[5];
    const float* wp  = (const float*)d_in[6];
    const float* bp  = (const float*)d_in[7];
    float* out = (float*)d_out;

    char* wsb = (char*)d_ws;
    __hip_bfloat16* xsk = (__hip_bfloat16*)wsb;                  // 25,165,824 B (K token-major, normalized)
    __hip_bfloat16* xsv = (__hip_bfloat16*)(wsb + 25165824ull);  // 25,165,824 B (V channel-major)
    __hip_bfloat16* qbf = (__hip_bfloat16*)(wsb + 50331648ull);  // 25,165,824 B (q bf16)
    float2* tbl = (float2*)(wsb + 75497472ull);                  // 32,768 B (rope table)
    unsigned int* gbits = (unsigned int*)(wsb + 75530240ull);    // 2,097,152 B (graph bits)
    __hip_bfloat16* wb  = (__hip_bfloat16*)(wsb + 77627392ull);  // 221,184 B (ws+wg bf16)
    __hip_bfloat16* wpb = wb + 110592;                           // 73,728 B (wp bf16)

    hipLaunchKernelGGL(k_rope_init, dim3(16),   dim3(256), 0, stream, tbl);
    hipLaunchKernelGGL(k_wcast,     dim3(144),  dim3(256), 0, stream, wsm, wg, wp, wb);
    hipLaunchKernelGGL(k_gmask,     dim3(2048), dim3(256), 0, stream, grph, gbits);
    hipLaunchKernelGGL(k_convm,     dim3(2048), dim3(256), 0, stream, x, wb, bsm, bgb, tbl, xsk, xsv, qbf);
    hipLaunchKernelGGL(k_attn,      dim3(6144), dim3(512), 0, stream, xsk, xsv, gbits, qbf, tbl, out);
    hipLaunchKernelGGL(k_oprojm,    dim3(3072), dim3(256), 0, stream, out, wpb, bp, out);
}

// Round 13
// 229.304 us; speedup vs baseline: 1.0471x; 1.0471x over previous
//
#include <hip/hip_runtime.h>
#include <hip/hip_bf16.h>

// Problem constants
#define B_    4
#define C_    192
#define C2_   384
#define PIX_  16384      // 128*128
#define NH_   6
#define BG_   1024
#define SCALE_ 0.17677669529663687f   // 32^-0.5
// exp(s*SCALE - SCALE) == exp2(fmaf(s, C1, -C1)), C1 = SCALE*log2(e).
// Valid because |s|<=1 (cosine of unit vectors) -> constant max M=1 is safe.
#define C1_ 0.2550348943f

typedef __attribute__((ext_vector_type(8))) short short8v;   // 8 bf16 = 4 VGPR
typedef __attribute__((ext_vector_type(4))) float f32x4;

// v_cvt_pk_bf16_f32: packs 2 f32 -> 2 bf16 (RNE) in one instruction.
__device__ __forceinline__ unsigned cvt_pk_bf16(float lo, float hi) {
    unsigned r;
    asm("v_cvt_pk_bf16_f32 %0, %1, %2" : "=v"(r) : "v"(lo), "v"(hi));
    return r;
}

// ---------------------------------------------------------------------------
// Kernel 0: RoPE cos/sin table
// ---------------------------------------------------------------------------
__global__ __launch_bounds__(256, 1)
void k_rope_init(float2* __restrict__ tbl) {
    int e = blockIdx.x * 256 + threadIdx.x;    // 4096 entries
    if (e >= 4096) return;
    int pos = e >> 4, j = e & 15;
    float freq = powf(10.0f, -0.25f * (float)j);
    float ang = (float)pos * freq;
    float sn, cs;
    sincosf(ang, &sn, &cs);
    tbl[e] = make_float2(cs, sn);
}

// ---------------------------------------------------------------------------
// Kernel 0b: graph int32 -> bitmask
// ---------------------------------------------------------------------------
__global__ __launch_bounds__(256, 4)
void k_gmask(const int* __restrict__ g, unsigned int* __restrict__ gbits) {
    int e = blockIdx.x * 256 + threadIdx.x;            // 524288 dwords
    const uint4* p = (const uint4*)(g + (size_t)e * 32);
    unsigned int m = 0u;
#pragma unroll
    for (int i = 0; i < 8; ++i) {
        uint4 v = p[i];
        m |= (v.x ? 1u : 0u) << (i * 4);
        m |= (v.y ? 1u : 0u) << (i * 4 + 1);
        m |= (v.z ? 1u : 0u) << (i * 4 + 2);
        m |= (v.w ? 1u : 0u) << (i * 4 + 3);
    }
    gbits[e] = m;
}

// ---------------------------------------------------------------------------
// Kernel 0c: cast w_sample ++ w_group ++ w_proj -> bf16
// ---------------------------------------------------------------------------
__global__ __launch_bounds__(256, 4)
void k_wcast(const float* __restrict__ wsm, const float* __restrict__ wgb,
             const float* __restrict__ wpj, __hip_bfloat16* __restrict__ wb)
{
    int e = (blockIdx.x * 256 + threadIdx.x) * 4;      // 147456 elems
    float4 v = (e < 73728) ? *(const float4*)(wsm + e)
             : (e < 110592) ? *(const float4*)(wgb + (e - 73728))
                            : *(const float4*)(wpj + (e - 110592));
    uint2 pk = make_uint2(cvt_pk_bf16(v.x, v.y), cvt_pk_bf16(v.z, v.w));
    *(uint2*)(wb + e) = pk;
}

// ---------------------------------------------------------------------------
// Kernel 1 (MFMA): fused 1x1 conv 192 -> 576, one block per 64-px tile,
// 512 threads = 8 waves (2x round-11 TLP at SAME staging cost), ONE barrier.
// Wave w: pb = (w&3)*16 px quarter, ob2 = (w>>2)*32 oc half; 6 hoisted
// x-frags (24 VGPR). launch_bounds(512,6) -> VGPR cap ~85 (r12's (256,8)
// cap=64 spilled: VGPR=32 + 27MB scratch writes; this keeps headroom).
// V octs: A=x,B=w -> D[px][oc], direct channel-major stores.
// K/Q octs: A=w,B=x -> D[oc][px]; per-lane single pixel -> in-reg bias/
// RoPE/norm (2 shfl_xor) and packed token-major stores. No LDS epilogues.
// ---------------------------------------------------------------------------
__global__ __launch_bounds__(512, 6)
void k_convm(const float* __restrict__ x, const __hip_bfloat16* __restrict__ wb,
             const float* __restrict__ bsm, const float* __restrict__ bgb,
             const float2* __restrict__ tbl,
             __hip_bfloat16* __restrict__ xsk, __hip_bfloat16* __restrict__ xsv,
             __hip_bfloat16* __restrict__ qbf)
{
    __shared__ __align__(16) char smem[25600];   // xt [64px][400B]
    const int bid = blockIdx.x;                  // 1024 = b(4) x pt(256)
    const int b = bid >> 8, pt = bid & 255;
    const int px0 = pt * 64;
    const int t = threadIdx.x;

    // ---- stage x tile [64 px][192 c] -> bf16 LDS, transposed (once) ----
    {
        const int px = t & 63, cq = t >> 6;           // cq: 8 groups x 24 ch
        const float* src = x + ((size_t)b * C_ + cq * 24) * PIX_ + px0 + px;
        char* row = smem + px * 400 + cq * 48;
#pragma unroll
        for (int i = 0; i < 3; ++i) {
            float f[8];
#pragma unroll
            for (int j = 0; j < 8; ++j) f[j] = src[(size_t)(i * 8 + j) * PIX_];
            uint4 pk4;
            pk4.x = cvt_pk_bf16(f[0], f[1]); pk4.y = cvt_pk_bf16(f[2], f[3]);
            pk4.z = cvt_pk_bf16(f[4], f[5]); pk4.w = cvt_pk_bf16(f[6], f[7]);
            *(uint4*)(row + i * 16) = pk4;
        }
    }
    __syncthreads();   // the ONLY barrier

    const int w = t >> 6, lane = t & 63;
    const int l15 = lane & 15, g = lane >> 4;
    const int pb  = (w & 3) * 16;    // px quarter
    const int ob2 = (w >> 2) * 32;   // oc half

    // ---- hoist x-frags (rows pb+l15): 6 frags = 24 VGPR ----
    short8v xf[6];
#pragma unroll
    for (int ks = 0; ks < 6; ++ks)
        xf[ks] = *(const short8v*)(smem + (pb + l15) * 400 + ks * 64 + g * 16);

    const f32x4 zz = {0.0f, 0.0f, 0.0f, 0.0f};

    // ================= V octs: A=x, B=w; direct store =====================
#pragma unroll
    for (int o2 = 0; o2 < 3; ++o2) {
        const int oct = 3 + o2;
        f32x4 acc0 = zz, acc1 = zz;
        const __hip_bfloat16* w0 = wb + (size_t)(oct * 64 + ob2 + l15) * C_;
        const __hip_bfloat16* w1 = w0 + 16 * C_;
#pragma unroll
        for (int ks = 0; ks < 6; ++ks) {
            const short8v b0 = *(const short8v*)(w0 + ks * 32 + g * 8);
            const short8v b1 = *(const short8v*)(w1 + ks * 32 + g * 8);
            acc0 = __builtin_amdgcn_mfma_f32_16x16x32_bf16(xf[ks], b0, acc0, 0, 0, 0);
            acc1 = __builtin_amdgcn_mfma_f32_16x16x32_bf16(xf[ks], b1, acc1, 0, 0, 0);
        }
        // acc0: (px = pb + 4g + j, oc = ob2 + l15); acc1: oc + 16
        const float bo0 = bsm[oct * 64 + ob2 + l15];
        const float bo1 = bsm[oct * 64 + ob2 + 16 + l15];
        uint2 p0 = make_uint2(cvt_pk_bf16(acc0[0] + bo0, acc0[1] + bo0),
                              cvt_pk_bf16(acc0[2] + bo0, acc0[3] + bo0));
        uint2 p1 = make_uint2(cvt_pk_bf16(acc1[0] + bo1, acc1[1] + bo1),
                              cvt_pk_bf16(acc1[2] + bo1, acc1[3] + bo1));
        __hip_bfloat16* d0 = xsv + (size_t)(b * C_ + o2 * 64 + ob2 + l15) * PIX_
                                 + px0 + pb + g * 4;
        *(uint2*)d0 = p0;
        *(uint2*)(d0 + (size_t)16 * PIX_) = p1;        // oc + 16
    }

    // ================= K octs: A=w, B=x -> D[oc][px]; in-reg norm =========
    // a0: (oc = ob2 + 4g + j, px = pb + l15); a1: oc + 16. One head/wave/oct.
#pragma unroll
    for (int o2 = 0; o2 < 3; ++o2) {
        const int oct = o2;
        f32x4 a0 = zz, a1 = zz;
        const __hip_bfloat16* w0 = wb + (size_t)(oct * 64 + ob2 + l15) * C_;
        const __hip_bfloat16* w1 = w0 + 16 * C_;
#pragma unroll
        for (int ks = 0; ks < 6; ++ks) {
            const short8v wf0 = *(const short8v*)(w0 + ks * 32 + g * 8);
            const short8v wf1 = *(const short8v*)(w1 + ks * 32 + g * 8);
            a0 = __builtin_amdgcn_mfma_f32_16x16x32_bf16(wf0, xf[ks], a0, 0, 0, 0);
            a1 = __builtin_amdgcn_mfma_f32_16x16x32_bf16(wf1, xf[ks], a1, 0, 0, 0);
        }
        const float4 bv0 = *(const float4*)(bsm + oct * 64 + ob2 + g * 4);
        const float4 bv1 = *(const float4*)(bsm + oct * 64 + ob2 + 16 + g * 4);
        a0[0] += bv0.x; a0[1] += bv0.y; a0[2] += bv0.z; a0[3] += bv0.w;
        a1[0] += bv1.x; a1[1] += bv1.y; a1[2] += bv1.z; a1[3] += bv1.w;
        float s = 0.0f;
#pragma unroll
        for (int j = 0; j < 4; ++j) {
            s = fmaf(a0[j], a0[j], s);
            s = fmaf(a1[j], a1[j], s);
        }
        s += __shfl_xor(s, 16); s += __shfl_xor(s, 32);
        const float inv = 1.0f / fmaxf(sqrtf(s), 1e-12f);
        uint2 q0 = make_uint2(cvt_pk_bf16(a0[0] * inv, a0[1] * inv),
                              cvt_pk_bf16(a0[2] * inv, a0[3] * inv));
        uint2 q1 = make_uint2(cvt_pk_bf16(a1[0] * inv, a1[1] * inv),
                              cvt_pk_bf16(a1[2] * inv, a1[3] * inv));
        __hip_bfloat16* d = xsk + ((size_t)b * PIX_ + px0 + pb + l15) * C_
                                + oct * 64 + ob2 + g * 4;
        *(uint2*)d        = q0;
        *(uint2*)(d + 16) = q1;                        // oc + 16
    }

    // ================= Q octs: A=w, B=x; in-reg RoPE + norm ================
    // Per-lane single pixel p -> single (n, bg).
    const int p  = px0 + pb + l15;
    const int r  = p >> 7, c = p & 127;
    const int n  = (r & 7) * 8 + (c & 7);
    const int bg = (b << 8) + ((r >> 3) << 4) + (c >> 3);
#pragma unroll
    for (int o2 = 0; o2 < 3; ++o2) {
        const int oct = 6 + o2;
        f32x4 a0 = zz, a1 = zz;
        const __hip_bfloat16* w0 = wb + (size_t)(oct * 64 + ob2 + l15) * C_;
        const __hip_bfloat16* w1 = w0 + 16 * C_;
#pragma unroll
        for (int ks = 0; ks < 6; ++ks) {
            const short8v wf0 = *(const short8v*)(w0 + ks * 32 + g * 8);
            const short8v wf1 = *(const short8v*)(w1 + ks * 32 + g * 8);
            a0 = __builtin_amdgcn_mfma_f32_16x16x32_bf16(wf0, xf[ks], a0, 0, 0, 0);
            a1 = __builtin_amdgcn_mfma_f32_16x16x32_bf16(wf1, xf[ks], a1, 0, 0, 0);
        }
        const float4 bv0 = *(const float4*)(bgb + (oct - 6) * 64 + ob2 + g * 4);
        const float4 bv1 = *(const float4*)(bgb + (oct - 6) * 64 + ob2 + 16 + g * 4);
        a0[0] += bv0.x; a0[1] += bv0.y; a0[2] += bv0.z; a0[3] += bv0.w;
        a1[0] += bv1.x; a1[1] += bv1.y; a1[2] += bv1.z; a1[3] += bv1.w;
        // RoPE: a0 = head-rel ch 4g+j -> pairs 2g, 2g+1; a1 -> pairs 8+2g, 8+2g+1
        {
            float2 cA = tbl[n * 16 + 2 * g], cB = tbl[n * 16 + 2 * g + 1];
            { float u0 = a0[0], u1 = a0[1];
              a0[0] = u0 * cA.x - u1 * cA.y; a0[1] = u1 * cA.x + u0 * cA.y; }
            { float u0 = a0[2], u1 = a0[3];
              a0[2] = u0 * cB.x - u1 * cB.y; a0[3] = u1 * cB.x + u0 * cB.y; }
            cA = tbl[n * 16 + 8 + 2 * g]; cB = tbl[n * 16 + 8 + 2 * g + 1];
            { float u0 = a1[0], u1 = a1[1];
              a1[0] = u0 * cA.x - u1 * cA.y; a1[1] = u1 * cA.x + u0 * cA.y; }
            { float u0 = a1[2], u1 = a1[3];
              a1[2] = u0 * cB.x - u1 * cB.y; a1[3] = u1 * cB.x + u0 * cB.y; }
        }
        float s = 0.0f;
#pragma unroll
        for (int j = 0; j < 4; ++j) {
            s = fmaf(a0[j], a0[j], s);
            s = fmaf(a1[j], a1[j], s);
        }
        s += __shfl_xor(s, 16); s += __shfl_xor(s, 32);
        const float inv = 1.0f / fmaxf(sqrtf(s), 1e-12f);
        uint2 q0 = make_uint2(cvt_pk_bf16(a0[0] * inv, a0[1] * inv),
                              cvt_pk_bf16(a0[2] * inv, a0[3] * inv));
        uint2 q1 = make_uint2(cvt_pk_bf16(a1[0] * inv, a1[1] * inv),
                              cvt_pk_bf16(a1[2] * inv, a1[3] * inv));
        const int hglob = (oct - 6) * 2 + (ob2 >> 5);
        __hip_bfloat16* d = qbf + (((size_t)bg * NH_ + hglob) * 64 + n) * 32 + g * 4;
        *(uint2*)d        = q0;
        *(uint2*)(d + 16) = q1;                        // ch + 16
    }
}

// ---------------------------------------------------------------------------
// Kernel 3 (MFMA): attention for one (bg, head).  (round-11 structure)
// ---------------------------------------------------------------------------
__global__ __launch_bounds__(512, 2)
void k_attn(const __hip_bfloat16* __restrict__ xsk, const __hip_bfloat16* __restrict__ xsv,
            const unsigned int* __restrict__ gbits, const __hip_bfloat16* __restrict__ qb,
            const float2* __restrict__ tbl, float* __restrict__ attn)
{
    __shared__ __align__(16) char smem[52736];
    const int bid0 = blockIdx.x;
    const int bid = (bid0 & 7) * 768 + (bid0 >> 3);    // 6144 = 8 x 768, bijective
    const int h = bid % NH_;
    const int bg = bid / NH_;
    const int b = bg >> 8, ph = (bg >> 4) & 15, pw = bg & 15;
    const int t = threadIdx.x;
    const int w = t >> 6, lane = t & 63;
    const int g = lane >> 4, l15 = lane & 15;
    const int rbase = (w & 3) * 16;        // q rows
    const int wcol  = w >> 2;              // kv half
    const int cb    = wcol * 128;
    const int cb32  = wcol * 4;

    // ---- B-frag: Q direct from global (issue early) ----
    const short8v qa = *(const short8v*)(qb +
        ((size_t)(bg * NH_ + h) * 64 + rbase + l15) * 32 + g * 8);

    // ---- stage K (rope only, pre-normalized) into kl: thread=(m,half) ----
    {
        const int m = t >> 1, half = t & 1;
        const int k0 = m >> 4, k1 = m & 15;
        const int rr = ph * 8 - 4 + k0, cc = pw * 8 - 4 + k1;
        const bool inb = ((unsigned)rr < 128u) && ((unsigned)cc < 128u);
        float kv[16];
        if (inb) {
            const uint4* pk = (const uint4*)(xsk +
                ((size_t)b * PIX_ + rr * 128 + cc) * C_ + h * 32 + half * 16);
            union { uint4 u; __hip_bfloat16 h8[8]; } r0, r1;
            r0.u = pk[0]; r1.u = pk[1];
#pragma unroll
            for (int d = 0; d < 8; ++d) {
                kv[d]     = __bfloat162float(r0.h8[d]);
                kv[8 + d] = __bfloat162float(r1.h8[d]);
            }
        } else {
#pragma unroll
            for (int d = 0; d < 16; ++d) kv[d] = 0.0f;
        }
        unsigned pk8[8];
#pragma unroll
        for (int p = 0; p < 8; ++p) {
            float2 cs = tbl[m * 16 + half * 8 + p];
            float a0 = kv[2 * p], a1 = kv[2 * p + 1];
            float e0 = a0 * cs.x - a1 * cs.y;
            float e1 = a1 * cs.x + a0 * cs.y;
            pk8[p] = cvt_pk_bf16(e0, e1);
        }
        *(uint4*)(smem + m * 80 + half * 32)      = make_uint4(pk8[0], pk8[1], pk8[2], pk8[3]);
        *(uint4*)(smem + m * 80 + half * 32 + 16) = make_uint4(pk8[4], pk8[5], pk8[6], pk8[7]);
    }

    // ---- stage V transposed into vl[d][kv] (528B rows) ----
    {
        const int d = t & 31, k0 = t >> 5;
        const int rr = ph * 8 - 4 + k0;
        const int c0 = pw * 8 - 4;
        char* dst = smem + 34816 + d * 528 + k0 * 32;
        const __hip_bfloat16* src = xsv + (size_t)(b * C_ + h * 32 + d) * PIX_ + rr * 128 + c0;
        const bool rok = (unsigned)rr < 128u;
        if (rok && pw >= 1 && pw <= 14) {
            const uint2* s2 = (const uint2*)src;   // 8B aligned
            uint2 a0 = s2[0], a1 = s2[1], a2 = s2[2], a3 = s2[3];
            ((uint4*)dst)[0] = make_uint4(a0.x, a0.y, a1.x, a1.y);
            ((uint4*)dst)[1] = make_uint4(a2.x, a2.y, a3.x, a3.y);
        } else {
            __hip_bfloat16* dh = (__hip_bfloat16*)dst;
            __hip_bfloat16 z = __float2bfloat16(0.0f);
#pragma unroll
            for (int i = 0; i < 16; ++i) {
                bool ok = rok && ((unsigned)(c0 + i) < 128u);
                dh[i] = ok ? src[i] : z;
            }
        }
    }

    // ---- stage graph bits: gb[q][9] uints ----
    {
        unsigned int* gbl = (unsigned int*)(smem + 20480);
        const int q = t >> 3, wd = t & 7;
        gbl[q * 9 + wd] = gbits[(size_t)bg * 512 + t];
    }
    __syncthreads();   // sync1

    // ---- sim = K Q^T (swapped): D[kt][q], lane: q = rbase+l15, kt = tile*16+4g+j
    f32x4 acc[8];
    const f32x4 zz = {0.0f, 0.0f, 0.0f, 0.0f};
#pragma unroll
    for (int tile = 0; tile < 8; ++tile) {
        const short8v kb = *(const short8v*)(smem + (cb + tile * 16 + l15) * 80 + g * 16);
        acc[tile] = __builtin_amdgcn_mfma_f32_16x16x32_bf16(kb, qa, zz, 0, 0, 0);
    }

    // ---- masked exp (constant max) + row sum (per-lane single q) ----
    const unsigned int* gbl = (const unsigned int*)(smem + 20480);
    float* reds = (float*)(smem + 51712);   // [64 q][2 wcol]
    {
        const int q = rbase + l15;
        const unsigned int wv[4] = { gbl[q * 9 + cb32], gbl[q * 9 + cb32 + 1],
                                     gbl[q * 9 + cb32 + 2], gbl[q * 9 + cb32 + 3] };
        float sm = 0.0f;
#pragma unroll
        for (int tile = 0; tile < 8; ++tile) {
            const unsigned int bits = wv[tile >> 1] >> ((tile & 1) * 16 + (g << 2));
#pragma unroll
            for (int j = 0; j < 4; ++j) {
                float e = __builtin_amdgcn_exp2f(fmaf(acc[tile][j], C1_, -C1_));
                e = ((bits >> j) & 1u) ? e : 0.0f;
                acc[tile][j] = e;
                sm += e;
            }
        }
        sm += __shfl_xor(sm, 16);
        sm += __shfl_xor(sm, 32);
        if (lane < 16) reds[q * 2 + wcol] = sm;
    }
    __syncthreads();   // sync2 (sum exchange; also: all QK kl reads done)

    float inv4[4];
#pragma unroll
    for (int j = 0; j < 4; ++j) {
        const int qq = rbase + (g << 2) + j;
        float2 rr2 = *(const float2*)&reds[qq * 2];
        inv4[j] = 1.0f / (rr2.x + rr2.y + 1e-37f);
    }

    // ---- write P (bf16, UNNORMALIZED): 8B per tile per lane ----
    char* plw = smem + w * 4352;   // [16 q][272B]
#pragma unroll
    for (int tile = 0; tile < 8; ++tile) {
        uint2 pw2 = make_uint2(cvt_pk_bf16(acc[tile][0], acc[tile][1]),
                               cvt_pk_bf16(acc[tile][2], acc[tile][3]));
        *(uint2*)(plw + l15 * 272 + tile * 32 + g * 8) = pw2;
    }

    // ---- PV ----
    f32x4 o0 = zz, o1 = zz;
#pragma unroll
    for (int ks = 0; ks < 4; ++ks) {
        const short8v pa  = *(const short8v*)(plw + l15 * 272 + (ks * 32 + g * 8) * 2);
        const short8v vb0 = *(const short8v*)(smem + 34816 + l15 * 528        + (cb + ks * 32 + g * 8) * 2);
        const short8v vb1 = *(const short8v*)(smem + 34816 + (16 + l15) * 528 + (cb + ks * 32 + g * 8) * 2);
        o0 = __builtin_amdgcn_mfma_f32_16x16x32_bf16(pa, vb0, o0, 0, 0, 0);
        o1 = __builtin_amdgcn_mfma_f32_16x16x32_bf16(pa, vb1, o1, 0, 0, 0);
    }
    __syncthreads();   // sync3

    // ---- cross-half reduce + normalize-on-output + store ----
    float* ob = (float*)smem;   // [64][33] f32
    if (wcol == 1) {
#pragma unroll
        for (int j = 0; j < 4; ++j) {
            const int q = rbase + g * 4 + j;
            ob[q * 33 + l15]      = o0[j];
            ob[q * 33 + 16 + l15] = o1[j];
        }
    }
    __syncthreads();   // sync4
    if (wcol == 0) {
#pragma unroll
        for (int j = 0; j < 4; ++j) {
            const int q = rbase + g * 4 + j;
            float v0 = (o0[j] + ob[q * 33 + l15])      * inv4[j];
            float v1 = (o1[j] + ob[q * 33 + 16 + l15]) * inv4[j];
            attn[((size_t)bg * 64 + q) * 192 + h * 32 + l15]      = v0;
            attn[((size_t)bg * 64 + q) * 192 + h * 32 + 16 + l15] = v1;
        }
    }
}

// ---------------------------------------------------------------------------
// Kernel 4 (MFMA): final projection out = attn @ wp^T + bp, in-place on d_out.
// ---------------------------------------------------------------------------
__global__ __launch_bounds__(256, 4)
void k_oprojm(const float* __restrict__ attn, const __hip_bfloat16* __restrict__ wpb,
              const float* __restrict__ bp, float* __restrict__ out)
{
    __shared__ __align__(16) char smem[25600];   // at [64r][400B] bf16 / ot f32 [64px][68]
    const int bid0 = blockIdx.x;
    const int bid = (bid0 & 7) * 384 + (bid0 >> 3);   // 3072 = 8 x 384, bijective
    const int oct = bid % 3;
    const int rt  = bid / 3;
    const int row0 = rt * 64;
    const int t = threadIdx.x;

    // ---- stage A: attn[row0..+64][192] f32 -> bf16 LDS (coalesced) ----
#pragma unroll
    for (int e0 = 0; e0 < 12; ++e0) {
        const int e = e0 * 256 + t;          // 3072 float4s
        const int r = e / 48, c4 = e % 48;
        float4 v = *(const float4*)(attn + (size_t)(row0 + r) * 192 + c4 * 4);
        uint2 pk = make_uint2(cvt_pk_bf16(v.x, v.y), cvt_pk_bf16(v.z, v.w));
        *(uint2*)(smem + r * 400 + c4 * 8) = pk;
    }
    __syncthreads();

    const int w = t >> 6, lane = t & 63;
    const int l15 = lane & 15, g = lane >> 4;
    const int mb = (w & 1) * 32;     // row quadrant
    const int nb = (w >> 1) * 32;    // oc quadrant

    const f32x4 zz = {0.0f, 0.0f, 0.0f, 0.0f};
    f32x4 acc00 = zz, acc01 = zz, acc10 = zz, acc11 = zz;
    const __hip_bfloat16* w0 = wpb + (size_t)(oct * 64 + nb + l15) * C_;
    const __hip_bfloat16* w1 = w0 + 16 * C_;
#pragma unroll
    for (int ks = 0; ks < 6; ++ks) {
        const short8v a0 = *(const short8v*)(smem + (mb + l15) * 400      + ks * 64 + g * 16);
        const short8v a1 = *(const short8v*)(smem + (mb + 16 + l15) * 400 + ks * 64 + g * 16);
        const short8v b0 = *(const short8v*)(w0 + ks * 32 + g * 8);
        const short8v b1 = *(const short8v*)(w1 + ks * 32 + g * 8);
        acc00 = __builtin_amdgcn_mfma_f32_16x16x32_bf16(a0, b0, acc00, 0, 0, 0);
        acc01 = __builtin_amdgcn_mfma_f32_16x16x32_bf16(a0, b1, acc01, 0, 0, 0);
        acc10 = __builtin_amdgcn_mfma_f32_16x16x32_bf16(a1, b0, acc10, 0, 0, 0);
        acc11 = __builtin_amdgcn_mfma_f32_16x16x32_bf16(a1, b1, acc11, 0, 0, 0);
    }
    __syncthreads();   // A-frag reads done -> overlay ot

    // ---- store transposed ot[px][oc] (68-float rows) ----
    float* ot = (float*)smem;
#pragma unroll
    for (int j = 0; j < 4; ++j) {
        ot[(mb + g * 4 + j) * 68      + nb + l15]      = acc00[j];
        ot[(mb + 16 + g * 4 + j) * 68 + nb + l15]      = acc10[j];
        ot[(mb + g * 4 + j) * 68      + nb + 16 + l15] = acc01[j];
        ot[(mb + 16 + g * 4 + j) * 68 + nb + 16 + l15] = acc11[j];
    }
    __syncthreads();

    // ---- epilogue: bias + coalesced f32 write ----
    {
        const int k = t & 15, pxi = t >> 4;
        const float4 bias4 = *(const float4*)(bp + oct * 64 + k * 4);
#pragma unroll
        for (int p = 0; p < 4; ++p) {
            const int px = p * 16 + pxi;
            float4 v = *(const float4*)&ot[px * 68 + k * 4];
            v.x += bias4.x; v.y += bias4.y; v.z += bias4.z; v.w += bias4.w;
            *(float4*)(out + (size_t)(row0 + px) * 192 + oct * 64 + k * 4) = v;
        }
    }
}

// ---------------------------------------------------------------------------
extern "C" void kernel_launch(void* const* d_in, const int* in_sizes, int n_in,
                              void* d_out, int out_size, void* d_ws, size_t ws_size,
                              hipStream_t stream)
{
    (void)in_sizes; (void)n_in; (void)out_size; (void)ws_size;
    const float* x   = (const float*)d_in[0];
    const int* grph  = (const int*)d_in[1];     // jnp bool -> int32 per harness
    const float* wg  = (const float*)d_in[2];
    const float* bgb = (const float*)d_in[3];
    const float* wsm = (const float*)d_in[4];
    const float* bsm = (const float*)d_in[5];
    const float* wp  = (const float*)d_in[6];
    const float* bp  = (const float*)d_in[7];
    float* out = (float*)d_out;

    char* wsb = (char*)d_ws;
    __hip_bfloat16* xsk = (__hip_bfloat16*)wsb;                  // 25,165,824 B (K token-major, normalized)
    __hip_bfloat16* xsv = (__hip_bfloat16*)(wsb + 25165824ull);  // 25,165,824 B (V channel-major)
    __hip_bfloat16* qbf = (__hip_bfloat16*)(wsb + 50331648ull);  // 25,165,824 B (q bf16)
    float2* tbl = (float2*)(wsb + 75497472ull);                  // 32,768 B (rope table)
    unsigned int* gbits = (unsigned int*)(wsb + 75530240ull);    // 2,097,152 B (graph bits)
    __hip_bfloat16* wb  = (__hip_bfloat16*)(wsb + 77627392ull);  // 221,184 B (ws+wg bf16)
    __hip_bfloat16* wpb = wb + 110592;                           // 73,728 B (wp bf16)

    hipLaunchKernelGGL(k_rope_init, dim3(16),   dim3(256), 0, stream, tbl);
    hipLaunchKernelGGL(k_wcast,     dim3(144),  dim3(256), 0, stream, wsm, wg, wp, wb);
    hipLaunchKernelGGL(k_gmask,     dim3(2048), dim3(256), 0, stream, grph, gbits);
    hipLaunchKernelGGL(k_convm,     dim3(1024), dim3(512), 0, stream, x, wb, bsm, bgb, tbl, xsk, xsv, qbf);
    hipLaunchKernelGGL(k_attn,      dim3(6144), dim3(512), 0, stream, xsk, xsv, gbits, qbf, tbl, out);
    hipLaunchKernelGGL(k_oprojm,    dim3(3072), dim3(256), 0, stream, out, wpb, bp, out);
}

// Round 14
// 180.350 us; speedup vs baseline: 1.3313x; 1.2714x over previous
//
#include <hip/hip_runtime.h>
#include <hip/hip_bf16.h>

// Problem constants
#define B_    4
#define C_    192
#define C2_   384
#define PIX_  16384      // 128*128
#define NH_   6
#define BG_   1024
#define SCALE_ 0.17677669529663687f   // 32^-0.5
// exp(s*SCALE - SCALE) == exp2(fmaf(s, C1, -C1)), C1 = SCALE*log2(e).
// Valid because |s|<=1 (cosine of unit vectors) -> constant max M=1 is safe.
#define C1_ 0.2550348943f

typedef __attribute__((ext_vector_type(8))) short short8v;   // 8 bf16 = 4 VGPR
typedef __attribute__((ext_vector_type(4))) float f32x4;

// v_cvt_pk_bf16_f32: packs 2 f32 -> 2 bf16 (RNE) in one instruction.
__device__ __forceinline__ unsigned cvt_pk_bf16(float lo, float hi) {
    unsigned r;
    asm("v_cvt_pk_bf16_f32 %0, %1, %2" : "=v"(r) : "v"(lo), "v"(hi));
    return r;
}

// ---------------------------------------------------------------------------
// Kernel 0 (merged prep): gmask (blocks 0..2047) + rope table (2048..2063)
// + weight cast (2064..2207). One launch instead of three.
// ---------------------------------------------------------------------------
__global__ __launch_bounds__(256, 4)
void k_prep(const int* __restrict__ g, unsigned int* __restrict__ gbits,
            float2* __restrict__ tbl,
            const float* __restrict__ wsm, const float* __restrict__ wgb,
            const float* __restrict__ wpj, __hip_bfloat16* __restrict__ wb)
{
    const int bidp = blockIdx.x;
    const int t = threadIdx.x;
    if (bidp < 2048) {
        // ---- graph int32 -> bitmask ----
        int e = bidp * 256 + t;                        // 524288 dwords
        const uint4* p = (const uint4*)(g + (size_t)e * 32);
        unsigned int m = 0u;
#pragma unroll
        for (int i = 0; i < 8; ++i) {
            uint4 v = p[i];
            m |= (v.x ? 1u : 0u) << (i * 4);
            m |= (v.y ? 1u : 0u) << (i * 4 + 1);
            m |= (v.z ? 1u : 0u) << (i * 4 + 2);
            m |= (v.w ? 1u : 0u) << (i * 4 + 3);
        }
        gbits[e] = m;
    } else if (bidp < 2064) {
        // ---- RoPE cos/sin table ----
        int e = (bidp - 2048) * 256 + t;               // 4096 entries
        int pos = e >> 4, j = e & 15;
        float freq = powf(10.0f, -0.25f * (float)j);
        float ang = (float)pos * freq;
        float sn, cs;
        sincosf(ang, &sn, &cs);
        tbl[e] = make_float2(cs, sn);
    } else {
        // ---- cast w_sample ++ w_group ++ w_proj -> bf16 ----
        int e = ((bidp - 2064) * 256 + t) * 4;         // 147456 elems
        float4 v = (e < 73728) ? *(const float4*)(wsm + e)
                 : (e < 110592) ? *(const float4*)(wgb + (e - 73728))
                                : *(const float4*)(wpj + (e - 110592));
        uint2 pk = make_uint2(cvt_pk_bf16(v.x, v.y), cvt_pk_bf16(v.z, v.w));
        *(uint2*)(wb + e) = pk;
    }
}

// ---------------------------------------------------------------------------
// Kernel 1 (MFMA): fused 1x1 conv 192 -> 576, ONE block per 64-px tile,
// ONE barrier total. (exact round-11 version: best measured, 83.5us)
// V octs (3-5): D[px][oc] (A=x, B=w) -> direct channel-major 8B stores.
// K octs (0-2) & Q octs (6-8): SWAPPED operands (A=w, B=x) -> D[oc][px]:
// in-register bias/norm (+RoPE for q) + 2 shfl_xor; packed 8B stores.
// ---------------------------------------------------------------------------
__global__ __launch_bounds__(256, 4)
void k_convm(const float* __restrict__ x, const __hip_bfloat16* __restrict__ wb,
             const float* __restrict__ bsm, const float* __restrict__ bgb,
             const float2* __restrict__ tbl,
             __hip_bfloat16* __restrict__ xsk, __hip_bfloat16* __restrict__ xsv,
             __hip_bfloat16* __restrict__ qbf)
{
    __shared__ __align__(16) char smem[25600];   // xt [64px][400B]
    const int bid = blockIdx.x;                  // 1024 = b(4) x pt(256)
    const int b = bid >> 8, pt = bid & 255;
    const int px0 = pt * 64;
    const int t = threadIdx.x;

    // ---- stage x tile [64 px][192 c] -> bf16 LDS, transposed (once) ----
    {
        const int px = t & 63, cq = t >> 6;
        const float* src = x + ((size_t)b * C_ + cq * 48) * PIX_ + px0 + px;
        char* row = smem + px * 400 + cq * 96;
#pragma unroll
        for (int i = 0; i < 6; ++i) {
            float f[8];
#pragma unroll
            for (int j = 0; j < 8; ++j) f[j] = src[(size_t)(i * 8 + j) * PIX_];
            uint4 pk4;
            pk4.x = cvt_pk_bf16(f[0], f[1]); pk4.y = cvt_pk_bf16(f[2], f[3]);
            pk4.z = cvt_pk_bf16(f[4], f[5]); pk4.w = cvt_pk_bf16(f[6], f[7]);
            *(uint4*)(row + i * 16) = pk4;
        }
    }
    __syncthreads();   // the ONLY barrier

    const int w = t >> 6, lane = t & 63;
    const int l15 = lane & 15, g = lane >> 4;
    const int mb = (w & 1) * 32;     // px quadrant
    const int nb = (w >> 1) * 32;    // oc quadrant

    // ---- hoist x-frags -- serve BOTH orientations ----
    short8v xf0[6], xf1[6];
#pragma unroll
    for (int ks = 0; ks < 6; ++ks) {
        xf0[ks] = *(const short8v*)(smem + (mb + l15) * 400      + ks * 64 + g * 16);
        xf1[ks] = *(const short8v*)(smem + (mb + 16 + l15) * 400 + ks * 64 + g * 16);
    }

    const f32x4 zz = {0.0f, 0.0f, 0.0f, 0.0f};

    // ================= V octs: A=x, B=w; direct store =====================
#pragma unroll
    for (int o2 = 0; o2 < 3; ++o2) {
        const int oct = 3 + o2;
        f32x4 acc00 = zz, acc01 = zz, acc10 = zz, acc11 = zz;
        const __hip_bfloat16* w0 = wb + (size_t)(oct * 64 + nb + l15) * C_;
        const __hip_bfloat16* w1 = w0 + 16 * C_;
#pragma unroll
        for (int ks = 0; ks < 6; ++ks) {
            const short8v b0 = *(const short8v*)(w0 + ks * 32 + g * 8);
            const short8v b1 = *(const short8v*)(w1 + ks * 32 + g * 8);
            acc00 = __builtin_amdgcn_mfma_f32_16x16x32_bf16(xf0[ks], b0, acc00, 0, 0, 0);
            acc01 = __builtin_amdgcn_mfma_f32_16x16x32_bf16(xf0[ks], b1, acc01, 0, 0, 0);
            acc10 = __builtin_amdgcn_mfma_f32_16x16x32_bf16(xf1[ks], b0, acc10, 0, 0, 0);
            acc11 = __builtin_amdgcn_mfma_f32_16x16x32_bf16(xf1[ks], b1, acc11, 0, 0, 0);
        }
        const float bo0 = bsm[oct * 64 + nb + l15];
        const float bo1 = bsm[oct * 64 + nb + 16 + l15];
        uint2 p00 = make_uint2(cvt_pk_bf16(acc00[0] + bo0, acc00[1] + bo0),
                               cvt_pk_bf16(acc00[2] + bo0, acc00[3] + bo0));
        uint2 p10 = make_uint2(cvt_pk_bf16(acc10[0] + bo0, acc10[1] + bo0),
                               cvt_pk_bf16(acc10[2] + bo0, acc10[3] + bo0));
        uint2 p01 = make_uint2(cvt_pk_bf16(acc01[0] + bo1, acc01[1] + bo1),
                               cvt_pk_bf16(acc01[2] + bo1, acc01[3] + bo1));
        uint2 p11 = make_uint2(cvt_pk_bf16(acc11[0] + bo1, acc11[1] + bo1),
                               cvt_pk_bf16(acc11[2] + bo1, acc11[3] + bo1));
        __hip_bfloat16* d0 = xsv + (size_t)(b * C_ + o2 * 64 + nb + l15) * PIX_
                                 + px0 + mb + g * 4;
        *(uint2*)d0        = p00;
        *(uint2*)(d0 + 16) = p10;                      // px + 16
        __hip_bfloat16* d1 = d0 + (size_t)16 * PIX_;   // oc + 16
        *(uint2*)d1        = p01;
        *(uint2*)(d1 + 16) = p11;
    }

    // ================= K octs: A=w, B=x -> D[oc][px]; in-reg norm =========
#pragma unroll
    for (int o2 = 0; o2 < 3; ++o2) {
        const int oct = o2;
        f32x4 a00 = zz, a01 = zz, a10 = zz, a11 = zz;
        const __hip_bfloat16* w0 = wb + (size_t)(oct * 64 + nb + l15) * C_;
        const __hip_bfloat16* w1 = w0 + 16 * C_;
#pragma unroll
        for (int ks = 0; ks < 6; ++ks) {
            const short8v wf0 = *(const short8v*)(w0 + ks * 32 + g * 8);
            const short8v wf1 = *(const short8v*)(w1 + ks * 32 + g * 8);
            a00 = __builtin_amdgcn_mfma_f32_16x16x32_bf16(wf0, xf0[ks], a00, 0, 0, 0);
            a01 = __builtin_amdgcn_mfma_f32_16x16x32_bf16(wf0, xf1[ks], a01, 0, 0, 0);
            a10 = __builtin_amdgcn_mfma_f32_16x16x32_bf16(wf1, xf0[ks], a10, 0, 0, 0);
            a11 = __builtin_amdgcn_mfma_f32_16x16x32_bf16(wf1, xf1[ks], a11, 0, 0, 0);
        }
        const float4 bv0 = *(const float4*)(bsm + oct * 64 + nb + g * 4);
        const float4 bv1 = *(const float4*)(bsm + oct * 64 + nb + 16 + g * 4);
        a00[0] += bv0.x; a00[1] += bv0.y; a00[2] += bv0.z; a00[3] += bv0.w;
        a01[0] += bv0.x; a01[1] += bv0.y; a01[2] += bv0.z; a01[3] += bv0.w;
        a10[0] += bv1.x; a10[1] += bv1.y; a10[2] += bv1.z; a10[3] += bv1.w;
        a11[0] += bv1.x; a11[1] += bv1.y; a11[2] += bv1.z; a11[3] += bv1.w;
        float s0 = 0.0f, s1 = 0.0f;
#pragma unroll
        for (int j = 0; j < 4; ++j) {
            s0 = fmaf(a00[j], a00[j], s0); s0 = fmaf(a10[j], a10[j], s0);
            s1 = fmaf(a01[j], a01[j], s1); s1 = fmaf(a11[j], a11[j], s1);
        }
        s0 += __shfl_xor(s0, 16); s0 += __shfl_xor(s0, 32);
        s1 += __shfl_xor(s1, 16); s1 += __shfl_xor(s1, 32);
        const float inv0 = 1.0f / fmaxf(sqrtf(s0), 1e-12f);
        const float inv1 = 1.0f / fmaxf(sqrtf(s1), 1e-12f);
        uint2 q00 = make_uint2(cvt_pk_bf16(a00[0] * inv0, a00[1] * inv0),
                               cvt_pk_bf16(a00[2] * inv0, a00[3] * inv0));
        uint2 q10 = make_uint2(cvt_pk_bf16(a10[0] * inv0, a10[1] * inv0),
                               cvt_pk_bf16(a10[2] * inv0, a10[3] * inv0));
        uint2 q01 = make_uint2(cvt_pk_bf16(a01[0] * inv1, a01[1] * inv1),
                               cvt_pk_bf16(a01[2] * inv1, a01[3] * inv1));
        uint2 q11 = make_uint2(cvt_pk_bf16(a11[0] * inv1, a11[1] * inv1),
                               cvt_pk_bf16(a11[2] * inv1, a11[3] * inv1));
        __hip_bfloat16* d0 = xsk + ((size_t)b * PIX_ + px0 + mb + l15) * C_
                                 + oct * 64 + nb + g * 4;
        *(uint2*)d0        = q00;
        *(uint2*)(d0 + 16) = q10;                      // oc + 16
        __hip_bfloat16* d1 = d0 + (size_t)16 * C_;     // px + 16
        *(uint2*)d1        = q01;
        *(uint2*)(d1 + 16) = q11;
    }

    // ================= Q octs: A=w, B=x; in-reg RoPE + norm ================
    const int r = pt >> 1;                       // pixel row (block-constant)
    const int c0q = (pt & 1) * 64 + mb + l15;    // col for sigma=0
    const int n0 = (r & 7) * 8 + (c0q & 7);
    const int n1 = (r & 7) * 8 + ((c0q + 16) & 7);
    const int bg0 = (b << 8) + ((r >> 3) << 4) + (c0q >> 3);
    const int bg1 = (b << 8) + ((r >> 3) << 4) + ((c0q + 16) >> 3);
#pragma unroll
    for (int o2 = 0; o2 < 3; ++o2) {
        const int oct = 6 + o2;
        f32x4 a00 = zz, a01 = zz, a10 = zz, a11 = zz;
        const __hip_bfloat16* w0 = wb + (size_t)(oct * 64 + nb + l15) * C_;
        const __hip_bfloat16* w1 = w0 + 16 * C_;
#pragma unroll
        for (int ks = 0; ks < 6; ++ks) {
            const short8v wf0 = *(const short8v*)(w0 + ks * 32 + g * 8);
            const short8v wf1 = *(const short8v*)(w1 + ks * 32 + g * 8);
            a00 = __builtin_amdgcn_mfma_f32_16x16x32_bf16(wf0, xf0[ks], a00, 0, 0, 0);
            a01 = __builtin_amdgcn_mfma_f32_16x16x32_bf16(wf0, xf1[ks], a01, 0, 0, 0);
            a10 = __builtin_amdgcn_mfma_f32_16x16x32_bf16(wf1, xf0[ks], a10, 0, 0, 0);
            a11 = __builtin_amdgcn_mfma_f32_16x16x32_bf16(wf1, xf1[ks], a11, 0, 0, 0);
        }
        const float4 bv0 = *(const float4*)(bgb + (oct - 6) * 64 + nb + g * 4);
        const float4 bv1 = *(const float4*)(bgb + (oct - 6) * 64 + nb + 16 + g * 4);
        a00[0] += bv0.x; a00[1] += bv0.y; a00[2] += bv0.z; a00[3] += bv0.w;
        a01[0] += bv0.x; a01[1] += bv0.y; a01[2] += bv0.z; a01[3] += bv0.w;
        a10[0] += bv1.x; a10[1] += bv1.y; a10[2] += bv1.z; a10[3] += bv1.w;
        a11[0] += bv1.x; a11[1] += bv1.y; a11[2] += bv1.z; a11[3] += bv1.w;
        {
            float2 cA, cB;
            cA = tbl[n0 * 16 + g * 2]; cB = tbl[n0 * 16 + g * 2 + 1];
            { float u0 = a00[0], u1 = a00[1];
              a00[0] = u0 * cA.x - u1 * cA.y; a00[1] = u1 * cA.x + u0 * cA.y; }
            { float u0 = a00[2], u1 = a00[3];
              a00[2] = u0 * cB.x - u1 * cB.y; a00[3] = u1 * cB.x + u0 * cB.y; }
            cA = tbl[n0 * 16 + 8 + g * 2]; cB = tbl[n0 * 16 + 8 + g * 2 + 1];
            { float u0 = a10[0], u1 = a10[1];
              a10[0] = u0 * cA.x - u1 * cA.y; a10[1] = u1 * cA.x + u0 * cA.y; }
            { float u0 = a10[2], u1 = a10[3];
              a10[2] = u0 * cB.x - u1 * cB.y; a10[3] = u1 * cB.x + u0 * cB.y; }
            cA = tbl[n1 * 16 + g * 2]; cB = tbl[n1 * 16 + g * 2 + 1];
            { float u0 = a01[0], u1 = a01[1];
              a01[0] = u0 * cA.x - u1 * cA.y; a01[1] = u1 * cA.x + u0 * cA.y; }
            { float u0 = a01[2], u1 = a01[3];
              a01[2] = u0 * cB.x - u1 * cB.y; a01[3] = u1 * cB.x + u0 * cB.y; }
            cA = tbl[n1 * 16 + 8 + g * 2]; cB = tbl[n1 * 16 + 8 + g * 2 + 1];
            { float u0 = a11[0], u1 = a11[1];
              a11[0] = u0 * cA.x - u1 * cA.y; a11[1] = u1 * cA.x + u0 * cA.y; }
            { float u0 = a11[2], u1 = a11[3];
              a11[2] = u0 * cB.x - u1 * cB.y; a11[3] = u1 * cB.x + u0 * cB.y; }
        }
        float s0 = 0.0f, s1 = 0.0f;
#pragma unroll
        for (int j = 0; j < 4; ++j) {
            s0 = fmaf(a00[j], a00[j], s0); s0 = fmaf(a10[j], a10[j], s0);
            s1 = fmaf(a01[j], a01[j], s1); s1 = fmaf(a11[j], a11[j], s1);
        }
        s0 += __shfl_xor(s0, 16); s0 += __shfl_xor(s0, 32);
        s1 += __shfl_xor(s1, 16); s1 += __shfl_xor(s1, 32);
        const float inv0 = 1.0f / fmaxf(sqrtf(s0), 1e-12f);
        const float inv1 = 1.0f / fmaxf(sqrtf(s1), 1e-12f);
        uint2 q00 = make_uint2(cvt_pk_bf16(a00[0] * inv0, a00[1] * inv0),
                               cvt_pk_bf16(a00[2] * inv0, a00[3] * inv0));
        uint2 q10 = make_uint2(cvt_pk_bf16(a10[0] * inv0, a10[1] * inv0),
                               cvt_pk_bf16(a10[2] * inv0, a10[3] * inv0));
        uint2 q01 = make_uint2(cvt_pk_bf16(a01[0] * inv1, a01[1] * inv1),
                               cvt_pk_bf16(a01[2] * inv1, a01[3] * inv1));
        uint2 q11 = make_uint2(cvt_pk_bf16(a11[0] * inv1, a11[1] * inv1),
                               cvt_pk_bf16(a11[2] * inv1, a11[3] * inv1));
        const int hglob = (oct - 6) * 2 + (nb >> 5);
        __hip_bfloat16* d0 = qbf + (((size_t)bg0 * NH_ + hglob) * 64 + n0) * 32 + g * 4;
        *(uint2*)d0        = q00;
        *(uint2*)(d0 + 16) = q10;                      // ch + 16
        __hip_bfloat16* d1 = qbf + (((size_t)bg1 * NH_ + hglob) * 64 + n1) * 32 + g * 4;
        *(uint2*)d1        = q01;
        *(uint2*)(d1 + 16) = q11;
    }
}

// ---------------------------------------------------------------------------
// Kernel 3 (MFMA): attention for one (bg, head).  (round-11 version)
// ---------------------------------------------------------------------------
__global__ __launch_bounds__(512, 2)
void k_attn(const __hip_bfloat16* __restrict__ xsk, const __hip_bfloat16* __restrict__ xsv,
            const unsigned int* __restrict__ gbits, const __hip_bfloat16* __restrict__ qb,
            const float2* __restrict__ tbl, float* __restrict__ attn)
{
    __shared__ __align__(16) char smem[52736];
    const int bid0 = blockIdx.x;
    const int bid = (bid0 & 7) * 768 + (bid0 >> 3);    // 6144 = 8 x 768, bijective
    const int h = bid % NH_;
    const int bg = bid / NH_;
    const int b = bg >> 8, ph = (bg >> 4) & 15, pw = bg & 15;
    const int t = threadIdx.x;
    const int w = t >> 6, lane = t & 63;
    const int g = lane >> 4, l15 = lane & 15;
    const int rbase = (w & 3) * 16;        // q rows
    const int wcol  = w >> 2;              // kv half
    const int cb    = wcol * 128;
    const int cb32  = wcol * 4;

    // ---- B-frag: Q direct from global (issue early) ----
    const short8v qa = *(const short8v*)(qb +
        ((size_t)(bg * NH_ + h) * 64 + rbase + l15) * 32 + g * 8);

    // ---- stage K (rope only, pre-normalized) into kl: thread=(m,half) ----
    {
        const int m = t >> 1, half = t & 1;
        const int k0 = m >> 4, k1 = m & 15;
        const int rr = ph * 8 - 4 + k0, cc = pw * 8 - 4 + k1;
        const bool inb = ((unsigned)rr < 128u) && ((unsigned)cc < 128u);
        float kv[16];
        if (inb) {
            const uint4* pk = (const uint4*)(xsk +
                ((size_t)b * PIX_ + rr * 128 + cc) * C_ + h * 32 + half * 16);
            union { uint4 u; __hip_bfloat16 h8[8]; } r0, r1;
            r0.u = pk[0]; r1.u = pk[1];
#pragma unroll
            for (int d = 0; d < 8; ++d) {
                kv[d]     = __bfloat162float(r0.h8[d]);
                kv[8 + d] = __bfloat162float(r1.h8[d]);
            }
        } else {
#pragma unroll
            for (int d = 0; d < 16; ++d) kv[d] = 0.0f;
        }
        unsigned pk8[8];
#pragma unroll
        for (int p = 0; p < 8; ++p) {
            float2 cs = tbl[m * 16 + half * 8 + p];
            float a0 = kv[2 * p], a1 = kv[2 * p + 1];
            float e0 = a0 * cs.x - a1 * cs.y;
            float e1 = a1 * cs.x + a0 * cs.y;
            pk8[p] = cvt_pk_bf16(e0, e1);
        }
        *(uint4*)(smem + m * 80 + half * 32)      = make_uint4(pk8[0], pk8[1], pk8[2], pk8[3]);
        *(uint4*)(smem + m * 80 + half * 32 + 16) = make_uint4(pk8[4], pk8[5], pk8[6], pk8[7]);
    }

    // ---- stage V transposed into vl[d][kv] (528B rows) ----
    {
        const int d = t & 31, k0 = t >> 5;
        const int rr = ph * 8 - 4 + k0;
        const int c0 = pw * 8 - 4;
        char* dst = smem + 34816 + d * 528 + k0 * 32;
        const __hip_bfloat16* src = xsv + (size_t)(b * C_ + h * 32 + d) * PIX_ + rr * 128 + c0;
        const bool rok = (unsigned)rr < 128u;
        if (rok && pw >= 1 && pw <= 14) {
            const uint2* s2 = (const uint2*)src;   // 8B aligned
            uint2 a0 = s2[0], a1 = s2[1], a2 = s2[2], a3 = s2[3];
            ((uint4*)dst)[0] = make_uint4(a0.x, a0.y, a1.x, a1.y);
            ((uint4*)dst)[1] = make_uint4(a2.x, a2.y, a3.x, a3.y);
        } else {
            __hip_bfloat16* dh = (__hip_bfloat16*)dst;
            __hip_bfloat16 z = __float2bfloat16(0.0f);
#pragma unroll
            for (int i = 0; i < 16; ++i) {
                bool ok = rok && ((unsigned)(c0 + i) < 128u);
                dh[i] = ok ? src[i] : z;
            }
        }
    }

    // ---- stage graph bits: gb[q][9] uints ----
    {
        unsigned int* gbl = (unsigned int*)(smem + 20480);
        const int q = t >> 3, wd = t & 7;
        gbl[q * 9 + wd] = gbits[(size_t)bg * 512 + t];
    }
    __syncthreads();   // sync1

    // ---- sim = K Q^T (swapped): D[kt][q], lane: q = rbase+l15, kt = tile*16+4g+j
    f32x4 acc[8];
    const f32x4 zz = {0.0f, 0.0f, 0.0f, 0.0f};
#pragma unroll
    for (int tile = 0; tile < 8; ++tile) {
        const short8v kb = *(const short8v*)(smem + (cb + tile * 16 + l15) * 80 + g * 16);
        acc[tile] = __builtin_amdgcn_mfma_f32_16x16x32_bf16(kb, qa, zz, 0, 0, 0);
    }

    // ---- masked exp (constant max) + row sum (per-lane single q) ----
    const unsigned int* gbl = (const unsigned int*)(smem + 20480);
    float* reds = (float*)(smem + 51712);   // [64 q][2 wcol]
    {
        const int q = rbase + l15;
        const unsigned int wv[4] = { gbl[q * 9 + cb32], gbl[q * 9 + cb32 + 1],
                                     gbl[q * 9 + cb32 + 2], gbl[q * 9 + cb32 + 3] };
        float sm = 0.0f;
#pragma unroll
        for (int tile = 0; tile < 8; ++tile) {
            const unsigned int bits = wv[tile >> 1] >> ((tile & 1) * 16 + (g << 2));
#pragma unroll
            for (int j = 0; j < 4; ++j) {
                float e = __builtin_amdgcn_exp2f(fmaf(acc[tile][j], C1_, -C1_));
                e = ((bits >> j) & 1u) ? e : 0.0f;
                acc[tile][j] = e;
                sm += e;
            }
        }
        sm += __shfl_xor(sm, 16);
        sm += __shfl_xor(sm, 32);
        if (lane < 16) reds[q * 2 + wcol] = sm;
    }
    __syncthreads();   // sync2 (sum exchange; also: all QK kl reads done)

    float inv4[4];
#pragma unroll
    for (int j = 0; j < 4; ++j) {
        const int qq = rbase + (g << 2) + j;
        float2 rr2 = *(const float2*)&reds[qq * 2];
        inv4[j] = 1.0f / (rr2.x + rr2.y + 1e-37f);
    }

    // ---- write P (bf16, UNNORMALIZED): 8B per tile per lane ----
    char* plw = smem + w * 4352;   // [16 q][272B]
#pragma unroll
    for (int tile = 0; tile < 8; ++tile) {
        uint2 pw2 = make_uint2(cvt_pk_bf16(acc[tile][0], acc[tile][1]),
                               cvt_pk_bf16(acc[tile][2], acc[tile][3]));
        *(uint2*)(plw + l15 * 272 + tile * 32 + g * 8) = pw2;
    }

    // ---- PV ----
    f32x4 o0 = zz, o1 = zz;
#pragma unroll
    for (int ks = 0; ks < 4; ++ks) {
        const short8v pa  = *(const short8v*)(plw + l15 * 272 + (ks * 32 + g * 8) * 2);
        const short8v vb0 = *(const short8v*)(smem + 34816 + l15 * 528        + (cb + ks * 32 + g * 8) * 2);
        const short8v vb1 = *(const short8v*)(smem + 34816 + (16 + l15) * 528 + (cb + ks * 32 + g * 8) * 2);
        o0 = __builtin_amdgcn_mfma_f32_16x16x32_bf16(pa, vb0, o0, 0, 0, 0);
        o1 = __builtin_amdgcn_mfma_f32_16x16x32_bf16(pa, vb1, o1, 0, 0, 0);
    }
    __syncthreads();   // sync3

    // ---- cross-half reduce + normalize-on-output + store ----
    float* ob = (float*)smem;   // [64][33] f32
    if (wcol == 1) {
#pragma unroll
        for (int j = 0; j < 4; ++j) {
            const int q = rbase + g * 4 + j;
            ob[q * 33 + l15]      = o0[j];
            ob[q * 33 + 16 + l15] = o1[j];
        }
    }
    __syncthreads();   // sync4
    if (wcol == 0) {
#pragma unroll
        for (int j = 0; j < 4; ++j) {
            const int q = rbase + g * 4 + j;
            float v0 = (o0[j] + ob[q * 33 + l15])      * inv4[j];
            float v1 = (o1[j] + ob[q * 33 + 16 + l15]) * inv4[j];
            attn[((size_t)bg * 64 + q) * 192 + h * 32 + l15]      = v0;
            attn[((size_t)bg * 64 + q) * 192 + h * 32 + 16 + l15] = v1;
        }
    }
}

// ---------------------------------------------------------------------------
// Kernel 4 (MFMA): final projection out = attn @ wp^T + bp, in-place.
// SWAPPED operands (A=wp rows, B=attn rows) -> D[oc][row]: each lane holds
// 4 consecutive oc at a fixed row -> bias + coalesced 16B f32 stores DIRECT
// from accumulators. No ot LDS round-trip; one barrier total.
// In-place safe: all attn reads happen in the stage phase before any store.
// ---------------------------------------------------------------------------
__global__ __launch_bounds__(256, 4)
void k_oprojm(const float* __restrict__ attn, const __hip_bfloat16* __restrict__ wpb,
              const float* __restrict__ bp, float* __restrict__ out)
{
    __shared__ __align__(16) char smem[25600];   // at [64r][400B] bf16
    const int bid0 = blockIdx.x;
    const int bid = (bid0 & 7) * 384 + (bid0 >> 3);   // 3072 = 8 x 384, bijective
    const int oct = bid % 3;
    const int rt  = bid / 3;
    const int row0 = rt * 64;
    const int t = threadIdx.x;

    // ---- stage A: attn[row0..+64][192] f32 -> bf16 LDS (coalesced) ----
#pragma unroll
    for (int e0 = 0; e0 < 12; ++e0) {
        const int e = e0 * 256 + t;          // 3072 float4s
        const int r = e / 48, c4 = e % 48;
        float4 v = *(const float4*)(attn + (size_t)(row0 + r) * 192 + c4 * 4);
        uint2 pk = make_uint2(cvt_pk_bf16(v.x, v.y), cvt_pk_bf16(v.z, v.w));
        *(uint2*)(smem + r * 400 + c4 * 8) = pk;
    }
    __syncthreads();   // the ONLY barrier

    const int w = t >> 6, lane = t & 63;
    const int l15 = lane & 15, g = lane >> 4;
    const int mb = (w & 1) * 32;     // row quadrant
    const int nb = (w >> 1) * 32;    // oc quadrant

    const f32x4 zz = {0.0f, 0.0f, 0.0f, 0.0f};
    f32x4 acc00 = zz, acc01 = zz, acc10 = zz, acc11 = zz;
    const __hip_bfloat16* w0 = wpb + (size_t)(oct * 64 + nb + l15) * C_;
    const __hip_bfloat16* w1 = w0 + 16 * C_;
#pragma unroll
    for (int ks = 0; ks < 6; ++ks) {
        const short8v a0 = *(const short8v*)(smem + (mb + l15) * 400      + ks * 64 + g * 16);
        const short8v a1 = *(const short8v*)(smem + (mb + 16 + l15) * 400 + ks * 64 + g * 16);
        const short8v b0 = *(const short8v*)(w0 + ks * 32 + g * 8);
        const short8v b1 = *(const short8v*)(w1 + ks * 32 + g * 8);
        // swapped: D[oc][row]
        acc00 = __builtin_amdgcn_mfma_f32_16x16x32_bf16(b0, a0, acc00, 0, 0, 0);
        acc01 = __builtin_amdgcn_mfma_f32_16x16x32_bf16(b0, a1, acc01, 0, 0, 0);
        acc10 = __builtin_amdgcn_mfma_f32_16x16x32_bf16(b1, a0, acc10, 0, 0, 0);
        acc11 = __builtin_amdgcn_mfma_f32_16x16x32_bf16(b1, a1, acc11, 0, 0, 0);
    }

    // ---- epilogue: bias + coalesced 16B f32 stores direct from accs ----
    // acc00: (oc = nb + 4g + j, row = mb + l15);  acc01: row + 16;
    // acc10: oc + 16;                              acc11: both + 16.
    const float4 bv0 = *(const float4*)(bp + oct * 64 + nb + g * 4);
    const float4 bv1 = *(const float4*)(bp + oct * 64 + nb + 16 + g * 4);
    float* d00 = out + (size_t)(row0 + mb + l15) * 192 + oct * 64 + nb + g * 4;
    float* d01 = out + (size_t)(row0 + mb + 16 + l15) * 192 + oct * 64 + nb + g * 4;
    float4 v;
    v = make_float4(acc00[0] + bv0.x, acc00[1] + bv0.y, acc00[2] + bv0.z, acc00[3] + bv0.w);
    *(float4*)d00 = v;
    v = make_float4(acc10[0] + bv1.x, acc10[1] + bv1.y, acc10[2] + bv1.z, acc10[3] + bv1.w);
    *(float4*)(d00 + 16) = v;
    v = make_float4(acc01[0] + bv0.x, acc01[1] + bv0.y, acc01[2] + bv0.z, acc01[3] + bv0.w);
    *(float4*)d01 = v;
    v = make_float4(acc11[0] + bv1.x, acc11[1] + bv1.y, acc11[2] + bv1.z, acc11[3] + bv1.w);
    *(float4*)(d01 + 16) = v;
}

// ---------------------------------------------------------------------------
extern "C" void kernel_launch(void* const* d_in, const int* in_sizes, int n_in,
                              void* d_out, int out_size, void* d_ws, size_t ws_size,
                              hipStream_t stream)
{
    (void)in_sizes; (void)n_in; (void)out_size; (void)ws_size;
    const float* x   = (const float*)d_in[0];
    const int* grph  = (const int*)d_in[1];     // jnp bool -> int32 per harness
    const float* wg  = (const float*)d_in[2];
    const float* bgb = (const float*)d_in[3];
    const float* wsm = (const float*)d_in[4];
    const float* bsm = (const float*)d_in[5];
    const float* wp  = (const float*)d_in[6];
    const float* bp  = (const float*)d_in[7];
    float* out = (float*)d_out;

    char* wsb = (char*)d_ws;
    __hip_bfloat16* xsk = (__hip_bfloat16*)wsb;                  // 25,165,824 B (K token-major, normalized)
    __hip_bfloat16* xsv = (__hip_bfloat16*)(wsb + 25165824ull);  // 25,165,824 B (V channel-major)
    __hip_bfloat16* qbf = (__hip_bfloat16*)(wsb + 50331648ull);  // 25,165,824 B (q bf16)
    float2* tbl = (float2*)(wsb + 75497472ull);                  // 32,768 B (rope table)
    unsigned int* gbits = (unsigned int*)(wsb + 75530240ull);    // 2,097,152 B (graph bits)
    __hip_bfloat16* wb  = (__hip_bfloat16*)(wsb + 77627392ull);  // 221,184 B (ws+wg bf16)
    __hip_bfloat16* wpb = wb + 110592;                           // 73,728 B (wp bf16)

    hipLaunchKernelGGL(k_prep,   dim3(2208), dim3(256), 0, stream,
                       grph, gbits, tbl, wsm, wg, wp, wb);
    hipLaunchKernelGGL(k_convm,  dim3(1024), dim3(256), 0, stream,
                       x, wb, bsm, bgb, tbl, xsk, xsv, qbf);
    hipLaunchKernelGGL(k_attn,   dim3(6144), dim3(512), 0, stream,
                       xsk, xsv, gbits, qbf, tbl, out);
    hipLaunchKernelGGL(k_oprojm, dim3(3072), dim3(256), 0, stream,
                       out, wpb, bp, out);
}

// Round 15
// 175.295 us; speedup vs baseline: 1.3697x; 1.0288x over previous
//
#include <hip/hip_runtime.h>
#include <hip/hip_bf16.h>

// Problem constants
#define B_    4
#define C_    192
#define C2_   384
#define PIX_  16384      // 128*128
#define NH_   6
#define BG_   1024
#define SCALE_ 0.17677669529663687f   // 32^-0.5
// exp(s*SCALE - SCALE) == exp2(fmaf(s, C1, -C1)), C1 = SCALE*log2(e).
// Valid because |s|<=1 (cosine of unit vectors) -> constant max M=1 is safe.
#define C1_ 0.2550348943f

typedef __attribute__((ext_vector_type(8))) short short8v;   // 8 bf16 = 4 VGPR
typedef __attribute__((ext_vector_type(4))) float f32x4;

// v_cvt_pk_bf16_f32: packs 2 f32 -> 2 bf16 (RNE) in one instruction.
__device__ __forceinline__ unsigned cvt_pk_bf16(float lo, float hi) {
    unsigned r;
    asm("v_cvt_pk_bf16_f32 %0, %1, %2" : "=v"(r) : "v"(lo), "v"(hi));
    return r;
}

// ---------------------------------------------------------------------------
// Kernel 0 (merged prep): gmask (blocks 0..2047) + rope table (2048..2063)
// + weight cast (2064..2207).
// ---------------------------------------------------------------------------
__global__ __launch_bounds__(256, 4)
void k_prep(const int* __restrict__ g, unsigned int* __restrict__ gbits,
            float2* __restrict__ tbl,
            const float* __restrict__ wsm, const float* __restrict__ wgb,
            const float* __restrict__ wpj, __hip_bfloat16* __restrict__ wb)
{
    const int bidp = blockIdx.x;
    const int t = threadIdx.x;
    if (bidp < 2048) {
        int e = bidp * 256 + t;                        // 524288 dwords
        const uint4* p = (const uint4*)(g + (size_t)e * 32);
        unsigned int m = 0u;
#pragma unroll
        for (int i = 0; i < 8; ++i) {
            uint4 v = p[i];
            m |= (v.x ? 1u : 0u) << (i * 4);
            m |= (v.y ? 1u : 0u) << (i * 4 + 1);
            m |= (v.z ? 1u : 0u) << (i * 4 + 2);
            m |= (v.w ? 1u : 0u) << (i * 4 + 3);
        }
        gbits[e] = m;
    } else if (bidp < 2064) {
        int e = (bidp - 2048) * 256 + t;               // 4096 entries
        int pos = e >> 4, j = e & 15;
        float freq = powf(10.0f, -0.25f * (float)j);
        float ang = (float)pos * freq;
        float sn, cs;
        sincosf(ang, &sn, &cs);
        tbl[e] = make_float2(cs, sn);
    } else {
        int e = ((bidp - 2064) * 256 + t) * 4;         // 147456 elems
        float4 v = (e < 73728) ? *(const float4*)(wsm + e)
                 : (e < 110592) ? *(const float4*)(wgb + (e - 73728))
                                : *(const float4*)(wpj + (e - 110592));
        uint2 pk = make_uint2(cvt_pk_bf16(v.x, v.y), cvt_pk_bf16(v.z, v.w));
        *(uint2*)(wb + e) = pk;
    }
}

// ---------------------------------------------------------------------------
// Weight prefetch: 12 frags (w0-half + w1-half) for one oct into registers.
// ---------------------------------------------------------------------------
__device__ __forceinline__ void wload(const int oct, const __hip_bfloat16* __restrict__ wb,
                                      const int nb, const int l15, const int g,
                                      short8v* __restrict__ dst)
{
    const __hip_bfloat16* w0 = wb + (size_t)(oct * 64 + nb + l15) * C_;
    const __hip_bfloat16* w1 = w0 + 16 * C_;
#pragma unroll
    for (int ks = 0; ks < 6; ++ks) {
        dst[ks]     = *(const short8v*)(w0 + ks * 32 + g * 8);
        dst[6 + ks] = *(const short8v*)(w1 + ks * 32 + g * 8);
    }
}

// ---------------------------------------------------------------------------
// One oct-tile of the fused conv (oct is a literal at every call site ->
// branches fold; all array indices static after inlining).
// ---------------------------------------------------------------------------
__device__ __forceinline__ void conv_oct(
    const int oct, const short8v* __restrict__ wc,
    const short8v* __restrict__ xf0, const short8v* __restrict__ xf1,
    const int b, const int px0, const int mb, const int nb,
    const int l15, const int g,
    const float* __restrict__ bsm, const float* __restrict__ bgb,
    const float2* __restrict__ tbl,
    const int n0, const int n1, const int bg0, const int bg1,
    __hip_bfloat16* __restrict__ xsk, __hip_bfloat16* __restrict__ xsv,
    __hip_bfloat16* __restrict__ qbf)
{
    const f32x4 zz = {0.0f, 0.0f, 0.0f, 0.0f};
    if (oct >= 3 && oct < 6) {
        // ---- V: A=x, B=w -> D[px][oc]; direct channel-major stores ----
        const int o2 = oct - 3;
        f32x4 acc00 = zz, acc01 = zz, acc10 = zz, acc11 = zz;
#pragma unroll
        for (int ks = 0; ks < 6; ++ks) {
            acc00 = __builtin_amdgcn_mfma_f32_16x16x32_bf16(xf0[ks], wc[ks],     acc00, 0, 0, 0);
            acc01 = __builtin_amdgcn_mfma_f32_16x16x32_bf16(xf0[ks], wc[6 + ks], acc01, 0, 0, 0);
            acc10 = __builtin_amdgcn_mfma_f32_16x16x32_bf16(xf1[ks], wc[ks],     acc10, 0, 0, 0);
            acc11 = __builtin_amdgcn_mfma_f32_16x16x32_bf16(xf1[ks], wc[6 + ks], acc11, 0, 0, 0);
        }
        const float bo0 = bsm[oct * 64 + nb + l15];
        const float bo1 = bsm[oct * 64 + nb + 16 + l15];
        uint2 p00 = make_uint2(cvt_pk_bf16(acc00[0] + bo0, acc00[1] + bo0),
                               cvt_pk_bf16(acc00[2] + bo0, acc00[3] + bo0));
        uint2 p10 = make_uint2(cvt_pk_bf16(acc10[0] + bo0, acc10[1] + bo0),
                               cvt_pk_bf16(acc10[2] + bo0, acc10[3] + bo0));
        uint2 p01 = make_uint2(cvt_pk_bf16(acc01[0] + bo1, acc01[1] + bo1),
                               cvt_pk_bf16(acc01[2] + bo1, acc01[3] + bo1));
        uint2 p11 = make_uint2(cvt_pk_bf16(acc11[0] + bo1, acc11[1] + bo1),
                               cvt_pk_bf16(acc11[2] + bo1, acc11[3] + bo1));
        __hip_bfloat16* d0 = xsv + (size_t)(b * C_ + o2 * 64 + nb + l15) * PIX_
                                 + px0 + mb + g * 4;
        *(uint2*)d0        = p00;
        *(uint2*)(d0 + 16) = p10;                      // px + 16
        __hip_bfloat16* d1 = d0 + (size_t)16 * PIX_;   // oc + 16
        *(uint2*)d1        = p01;
        *(uint2*)(d1 + 16) = p11;
    } else if (oct < 3) {
        // ---- K: A=w, B=x -> D[oc][px]; in-reg bias+norm; token-major ----
        f32x4 a00 = zz, a01 = zz, a10 = zz, a11 = zz;
#pragma unroll
        for (int ks = 0; ks < 6; ++ks) {
            a00 = __builtin_amdgcn_mfma_f32_16x16x32_bf16(wc[ks],     xf0[ks], a00, 0, 0, 0);
            a01 = __builtin_amdgcn_mfma_f32_16x16x32_bf16(wc[ks],     xf1[ks], a01, 0, 0, 0);
            a10 = __builtin_amdgcn_mfma_f32_16x16x32_bf16(wc[6 + ks], xf0[ks], a10, 0, 0, 0);
            a11 = __builtin_amdgcn_mfma_f32_16x16x32_bf16(wc[6 + ks], xf1[ks], a11, 0, 0, 0);
        }
        const float4 bv0 = *(const float4*)(bsm + oct * 64 + nb + g * 4);
        const float4 bv1 = *(const float4*)(bsm + oct * 64 + nb + 16 + g * 4);
        a00[0] += bv0.x; a00[1] += bv0.y; a00[2] += bv0.z; a00[3] += bv0.w;
        a01[0] += bv0.x; a01[1] += bv0.y; a01[2] += bv0.z; a01[3] += bv0.w;
        a10[0] += bv1.x; a10[1] += bv1.y; a10[2] += bv1.z; a10[3] += bv1.w;
        a11[0] += bv1.x; a11[1] += bv1.y; a11[2] += bv1.z; a11[3] += bv1.w;
        float s0 = 0.0f, s1 = 0.0f;
#pragma unroll
        for (int j = 0; j < 4; ++j) {
            s0 = fmaf(a00[j], a00[j], s0); s0 = fmaf(a10[j], a10[j], s0);
            s1 = fmaf(a01[j], a01[j], s1); s1 = fmaf(a11[j], a11[j], s1);
        }
        s0 += __shfl_xor(s0, 16); s0 += __shfl_xor(s0, 32);
        s1 += __shfl_xor(s1, 16); s1 += __shfl_xor(s1, 32);
        const float inv0 = 1.0f / fmaxf(sqrtf(s0), 1e-12f);
        const float inv1 = 1.0f / fmaxf(sqrtf(s1), 1e-12f);
        uint2 q00 = make_uint2(cvt_pk_bf16(a00[0] * inv0, a00[1] * inv0),
                               cvt_pk_bf16(a00[2] * inv0, a00[3] * inv0));
        uint2 q10 = make_uint2(cvt_pk_bf16(a10[0] * inv0, a10[1] * inv0),
                               cvt_pk_bf16(a10[2] * inv0, a10[3] * inv0));
        uint2 q01 = make_uint2(cvt_pk_bf16(a01[0] * inv1, a01[1] * inv1),
                               cvt_pk_bf16(a01[2] * inv1, a01[3] * inv1));
        uint2 q11 = make_uint2(cvt_pk_bf16(a11[0] * inv1, a11[1] * inv1),
                               cvt_pk_bf16(a11[2] * inv1, a11[3] * inv1));
        __hip_bfloat16* d0 = xsk + ((size_t)b * PIX_ + px0 + mb + l15) * C_
                                 + oct * 64 + nb + g * 4;
        *(uint2*)d0        = q00;
        *(uint2*)(d0 + 16) = q10;                      // oc + 16
        __hip_bfloat16* d1 = d0 + (size_t)16 * C_;     // px + 16
        *(uint2*)d1        = q01;
        *(uint2*)(d1 + 16) = q11;
    } else {
        // ---- Q: A=w, B=x; in-reg bias+RoPE+norm ----
        f32x4 a00 = zz, a01 = zz, a10 = zz, a11 = zz;
#pragma unroll
        for (int ks = 0; ks < 6; ++ks) {
            a00 = __builtin_amdgcn_mfma_f32_16x16x32_bf16(wc[ks],     xf0[ks], a00, 0, 0, 0);
            a01 = __builtin_amdgcn_mfma_f32_16x16x32_bf16(wc[ks],     xf1[ks], a01, 0, 0, 0);
            a10 = __builtin_amdgcn_mfma_f32_16x16x32_bf16(wc[6 + ks], xf0[ks], a10, 0, 0, 0);
            a11 = __builtin_amdgcn_mfma_f32_16x16x32_bf16(wc[6 + ks], xf1[ks], a11, 0, 0, 0);
        }
        const float4 bv0 = *(const float4*)(bgb + (oct - 6) * 64 + nb + g * 4);
        const float4 bv1 = *(const float4*)(bgb + (oct - 6) * 64 + nb + 16 + g * 4);
        a00[0] += bv0.x; a00[1] += bv0.y; a00[2] += bv0.z; a00[3] += bv0.w;
        a01[0] += bv0.x; a01[1] += bv0.y; a01[2] += bv0.z; a01[3] += bv0.w;
        a10[0] += bv1.x; a10[1] += bv1.y; a10[2] += bv1.z; a10[3] += bv1.w;
        a11[0] += bv1.x; a11[1] += bv1.y; a11[2] += bv1.z; a11[3] += bv1.w;
        {
            float2 cA, cB;
            cA = tbl[n0 * 16 + g * 2]; cB = tbl[n0 * 16 + g * 2 + 1];
            { float u0 = a00[0], u1 = a00[1];
              a00[0] = u0 * cA.x - u1 * cA.y; a00[1] = u1 * cA.x + u0 * cA.y; }
            { float u0 = a00[2], u1 = a00[3];
              a00[2] = u0 * cB.x - u1 * cB.y; a00[3] = u1 * cB.x + u0 * cB.y; }
            cA = tbl[n0 * 16 + 8 + g * 2]; cB = tbl[n0 * 16 + 8 + g * 2 + 1];
            { float u0 = a10[0], u1 = a10[1];
              a10[0] = u0 * cA.x - u1 * cA.y; a10[1] = u1 * cA.x + u0 * cA.y; }
            { float u0 = a10[2], u1 = a10[3];
              a10[2] = u0 * cB.x - u1 * cB.y; a10[3] = u1 * cB.x + u0 * cB.y; }
            cA = tbl[n1 * 16 + g * 2]; cB = tbl[n1 * 16 + g * 2 + 1];
            { float u0 = a01[0], u1 = a01[1];
              a01[0] = u0 * cA.x - u1 * cA.y; a01[1] = u1 * cA.x + u0 * cA.y; }
            { float u0 = a01[2], u1 = a01[3];
              a01[2] = u0 * cB.x - u1 * cB.y; a01[3] = u1 * cB.x + u0 * cB.y; }
            cA = tbl[n1 * 16 + 8 + g * 2]; cB = tbl[n1 * 16 + 8 + g * 2 + 1];
            { float u0 = a11[0], u1 = a11[1];
              a11[0] = u0 * cA.x - u1 * cA.y; a11[1] = u1 * cA.x + u0 * cA.y; }
            { float u0 = a11[2], u1 = a11[3];
              a11[2] = u0 * cB.x - u1 * cB.y; a11[3] = u1 * cB.x + u0 * cB.y; }
        }
        float s0 = 0.0f, s1 = 0.0f;
#pragma unroll
        for (int j = 0; j < 4; ++j) {
            s0 = fmaf(a00[j], a00[j], s0); s0 = fmaf(a10[j], a10[j], s0);
            s1 = fmaf(a01[j], a01[j], s1); s1 = fmaf(a11[j], a11[j], s1);
        }
        s0 += __shfl_xor(s0, 16); s0 += __shfl_xor(s0, 32);
        s1 += __shfl_xor(s1, 16); s1 += __shfl_xor(s1, 32);
        const float inv0 = 1.0f / fmaxf(sqrtf(s0), 1e-12f);
        const float inv1 = 1.0f / fmaxf(sqrtf(s1), 1e-12f);
        uint2 q00 = make_uint2(cvt_pk_bf16(a00[0] * inv0, a00[1] * inv0),
                               cvt_pk_bf16(a00[2] * inv0, a00[3] * inv0));
        uint2 q10 = make_uint2(cvt_pk_bf16(a10[0] * inv0, a10[1] * inv0),
                               cvt_pk_bf16(a10[2] * inv0, a10[3] * inv0));
        uint2 q01 = make_uint2(cvt_pk_bf16(a01[0] * inv1, a01[1] * inv1),
                               cvt_pk_bf16(a01[2] * inv1, a01[3] * inv1));
        uint2 q11 = make_uint2(cvt_pk_bf16(a11[0] * inv1, a11[1] * inv1),
                               cvt_pk_bf16(a11[2] * inv1, a11[3] * inv1));
        const int hglob = (oct - 6) * 2 + (nb >> 5);
        __hip_bfloat16* d0 = qbf + (((size_t)bg0 * NH_ + hglob) * 64 + n0) * 32 + g * 4;
        *(uint2*)d0        = q00;
        *(uint2*)(d0 + 16) = q10;                      // ch + 16
        __hip_bfloat16* d1 = qbf + (((size_t)bg1 * NH_ + hglob) * 64 + n1) * 32 + g * 4;
        *(uint2*)d1        = q01;
        *(uint2*)(d1 + 16) = q11;
    }
}

// ---------------------------------------------------------------------------
// Kernel 1 (MFMA): fused 1x1 conv 192 -> 576, ONE block per 64-px tile,
// ONE barrier. Register-double-buffered weight prefetch: wload(oct+1)
// issued BEFORE conv_oct(oct) -> next oct's 12 L2 loads land under current
// oct's MFMA+epilogue. launch_bounds(256,2): full VGPR room (target ~180),
// 2 blocks/CU. r12/r13 showed occupancy-up/VGPR-down regresses; this is
// the opposite corner.
// ---------------------------------------------------------------------------
__global__ __launch_bounds__(256, 2)
void k_convm(const float* __restrict__ x, const __hip_bfloat16* __restrict__ wb,
             const float* __restrict__ bsm, const float* __restrict__ bgb,
             const float2* __restrict__ tbl,
             __hip_bfloat16* __restrict__ xsk, __hip_bfloat16* __restrict__ xsv,
             __hip_bfloat16* __restrict__ qbf)
{
    __shared__ __align__(16) char smem[25600];   // xt [64px][400B]
    const int bid = blockIdx.x;                  // 1024 = b(4) x pt(256)
    const int b = bid >> 8, pt = bid & 255;
    const int px0 = pt * 64;
    const int t = threadIdx.x;

    // ---- stage x tile [64 px][192 c] -> bf16 LDS, transposed (once) ----
    {
        const int px = t & 63, cq = t >> 6;
        const float* src = x + ((size_t)b * C_ + cq * 48) * PIX_ + px0 + px;
        char* row = smem + px * 400 + cq * 96;
#pragma unroll
        for (int i = 0; i < 6; ++i) {
            float f[8];
#pragma unroll
            for (int j = 0; j < 8; ++j) f[j] = src[(size_t)(i * 8 + j) * PIX_];
            uint4 pk4;
            pk4.x = cvt_pk_bf16(f[0], f[1]); pk4.y = cvt_pk_bf16(f[2], f[3]);
            pk4.z = cvt_pk_bf16(f[4], f[5]); pk4.w = cvt_pk_bf16(f[6], f[7]);
            *(uint4*)(row + i * 16) = pk4;
        }
    }
    __syncthreads();   // the ONLY barrier

    const int w = t >> 6, lane = t & 63;
    const int l15 = lane & 15, g = lane >> 4;
    const int mb = (w & 1) * 32;     // px quadrant
    const int nb = (w >> 1) * 32;    // oc quadrant

    // ---- hoist x-frags ----
    short8v xf0[6], xf1[6];
#pragma unroll
    for (int ks = 0; ks < 6; ++ks) {
        xf0[ks] = *(const short8v*)(smem + (mb + l15) * 400      + ks * 64 + g * 16);
        xf1[ks] = *(const short8v*)(smem + (mb + 16 + l15) * 400 + ks * 64 + g * 16);
    }

    // ---- Q-path constants (per-lane pixel mapping) ----
    const int r = pt >> 1;
    const int c0q = (pt & 1) * 64 + mb + l15;
    const int n0 = (r & 7) * 8 + (c0q & 7);
    const int n1 = (r & 7) * 8 + ((c0q + 16) & 7);
    const int bg0 = (b << 8) + ((r >> 3) << 4) + (c0q >> 3);
    const int bg1 = (b << 8) + ((r >> 3) << 4) + ((c0q + 16) >> 3);

    // ---- software-pipelined oct loop (register double buffer) ----
    short8v wA[12], wB[12];
    wload(0, wb, nb, l15, g, wA);

    wload(1, wb, nb, l15, g, wB);
    conv_oct(0, wA, xf0, xf1, b, px0, mb, nb, l15, g, bsm, bgb, tbl, n0, n1, bg0, bg1, xsk, xsv, qbf);
    wload(2, wb, nb, l15, g, wA);
    conv_oct(1, wB, xf0, xf1, b, px0, mb, nb, l15, g, bsm, bgb, tbl, n0, n1, bg0, bg1, xsk, xsv, qbf);
    wload(3, wb, nb, l15, g, wB);
    conv_oct(2, wA, xf0, xf1, b, px0, mb, nb, l15, g, bsm, bgb, tbl, n0, n1, bg0, bg1, xsk, xsv, qbf);
    wload(4, wb, nb, l15, g, wA);
    conv_oct(3, wB, xf0, xf1, b, px0, mb, nb, l15, g, bsm, bgb, tbl, n0, n1, bg0, bg1, xsk, xsv, qbf);
    wload(5, wb, nb, l15, g, wB);
    conv_oct(4, wA, xf0, xf1, b, px0, mb, nb, l15, g, bsm, bgb, tbl, n0, n1, bg0, bg1, xsk, xsv, qbf);
    wload(6, wb, nb, l15, g, wA);
    conv_oct(5, wB, xf0, xf1, b, px0, mb, nb, l15, g, bsm, bgb, tbl, n0, n1, bg0, bg1, xsk, xsv, qbf);
    wload(7, wb, nb, l15, g, wB);
    conv_oct(6, wA, xf0, xf1, b, px0, mb, nb, l15, g, bsm, bgb, tbl, n0, n1, bg0, bg1, xsk, xsv, qbf);
    wload(8, wb, nb, l15, g, wA);
    conv_oct(7, wB, xf0, xf1, b, px0, mb, nb, l15, g, bsm, bgb, tbl, n0, n1, bg0, bg1, xsk, xsv, qbf);
    conv_oct(8, wA, xf0, xf1, b, px0, mb, nb, l15, g, bsm, bgb, tbl, n0, n1, bg0, bg1, xsk, xsv, qbf);
}

// ---------------------------------------------------------------------------
// Kernel 3 (MFMA): attention for one (bg, head).  (round-11 version)
// ---------------------------------------------------------------------------
__global__ __launch_bounds__(512, 2)
void k_attn(const __hip_bfloat16* __restrict__ xsk, const __hip_bfloat16* __restrict__ xsv,
            const unsigned int* __restrict__ gbits, const __hip_bfloat16* __restrict__ qb,
            const float2* __restrict__ tbl, float* __restrict__ attn)
{
    __shared__ __align__(16) char smem[52736];
    const int bid0 = blockIdx.x;
    const int bid = (bid0 & 7) * 768 + (bid0 >> 3);    // 6144 = 8 x 768, bijective
    const int h = bid % NH_;
    const int bg = bid / NH_;
    const int b = bg >> 8, ph = (bg >> 4) & 15, pw = bg & 15;
    const int t = threadIdx.x;
    const int w = t >> 6, lane = t & 63;
    const int g = lane >> 4, l15 = lane & 15;
    const int rbase = (w & 3) * 16;        // q rows
    const int wcol  = w >> 2;              // kv half
    const int cb    = wcol * 128;
    const int cb32  = wcol * 4;

    // ---- B-frag: Q direct from global (issue early) ----
    const short8v qa = *(const short8v*)(qb +
        ((size_t)(bg * NH_ + h) * 64 + rbase + l15) * 32 + g * 8);

    // ---- stage K (rope only, pre-normalized) into kl: thread=(m,half) ----
    {
        const int m = t >> 1, half = t & 1;
        const int k0 = m >> 4, k1 = m & 15;
        const int rr = ph * 8 - 4 + k0, cc = pw * 8 - 4 + k1;
        const bool inb = ((unsigned)rr < 128u) && ((unsigned)cc < 128u);
        float kv[16];
        if (inb) {
            const uint4* pk = (const uint4*)(xsk +
                ((size_t)b * PIX_ + rr * 128 + cc) * C_ + h * 32 + half * 16);
            union { uint4 u; __hip_bfloat16 h8[8]; } r0, r1;
            r0.u = pk[0]; r1.u = pk[1];
#pragma unroll
            for (int d = 0; d < 8; ++d) {
                kv[d]     = __bfloat162float(r0.h8[d]);
                kv[8 + d] = __bfloat162float(r1.h8[d]);
            }
        } else {
#pragma unroll
            for (int d = 0; d < 16; ++d) kv[d] = 0.0f;
        }
        unsigned pk8[8];
#pragma unroll
        for (int p = 0; p < 8; ++p) {
            float2 cs = tbl[m * 16 + half * 8 + p];
            float a0 = kv[2 * p], a1 = kv[2 * p + 1];
            float e0 = a0 * cs.x - a1 * cs.y;
            float e1 = a1 * cs.x + a0 * cs.y;
            pk8[p] = cvt_pk_bf16(e0, e1);
        }
        *(uint4*)(smem + m * 80 + half * 32)      = make_uint4(pk8[0], pk8[1], pk8[2], pk8[3]);
        *(uint4*)(smem + m * 80 + half * 32 + 16) = make_uint4(pk8[4], pk8[5], pk8[6], pk8[7]);
    }

    // ---- stage V transposed into vl[d][kv] (528B rows) ----
    {
        const int d = t & 31, k0 = t >> 5;
        const int rr = ph * 8 - 4 + k0;
        const int c0 = pw * 8 - 4;
        char* dst = smem + 34816 + d * 528 + k0 * 32;
        const __hip_bfloat16* src = xsv + (size_t)(b * C_ + h * 32 + d) * PIX_ + rr * 128 + c0;
        const bool rok = (unsigned)rr < 128u;
        if (rok && pw >= 1 && pw <= 14) {
            const uint2* s2 = (const uint2*)src;   // 8B aligned
            uint2 a0 = s2[0], a1 = s2[1], a2 = s2[2], a3 = s2[3];
            ((uint4*)dst)[0] = make_uint4(a0.x, a0.y, a1.x, a1.y);
            ((uint4*)dst)[1] = make_uint4(a2.x, a2.y, a3.x, a3.y);
        } else {
            __hip_bfloat16* dh = (__hip_bfloat16*)dst;
            __hip_bfloat16 z = __float2bfloat16(0.0f);
#pragma unroll
            for (int i = 0; i < 16; ++i) {
                bool ok = rok && ((unsigned)(c0 + i) < 128u);
                dh[i] = ok ? src[i] : z;
            }
        }
    }

    // ---- stage graph bits: gb[q][9] uints ----
    {
        unsigned int* gbl = (unsigned int*)(smem + 20480);
        const int q = t >> 3, wd = t & 7;
        gbl[q * 9 + wd] = gbits[(size_t)bg * 512 + t];
    }
    __syncthreads();   // sync1

    // ---- sim = K Q^T (swapped): D[kt][q], lane: q = rbase+l15, kt = tile*16+4g+j
    f32x4 acc[8];
    const f32x4 zz = {0.0f, 0.0f, 0.0f, 0.0f};
#pragma unroll
    for (int tile = 0; tile < 8; ++tile) {
        const short8v kb = *(const short8v*)(smem + (cb + tile * 16 + l15) * 80 + g * 16);
        acc[tile] = __builtin_amdgcn_mfma_f32_16x16x32_bf16(kb, qa, zz, 0, 0, 0);
    }

    // ---- masked exp (constant max) + row sum (per-lane single q) ----
    const unsigned int* gbl = (const unsigned int*)(smem + 20480);
    float* reds = (float*)(smem + 51712);   // [64 q][2 wcol]
    {
        const int q = rbase + l15;
        const unsigned int wv[4] = { gbl[q * 9 + cb32], gbl[q * 9 + cb32 + 1],
                                     gbl[q * 9 + cb32 + 2], gbl[q * 9 + cb32 + 3] };
        float sm = 0.0f;
#pragma unroll
        for (int tile = 0; tile < 8; ++tile) {
            const unsigned int bits = wv[tile >> 1] >> ((tile & 1) * 16 + (g << 2));
#pragma unroll
            for (int j = 0; j < 4; ++j) {
                float e = __builtin_amdgcn_exp2f(fmaf(acc[tile][j], C1_, -C1_));
                e = ((bits >> j) & 1u) ? e : 0.0f;
                acc[tile][j] = e;
                sm += e;
            }
        }
        sm += __shfl_xor(sm, 16);
        sm += __shfl_xor(sm, 32);
        if (lane < 16) reds[q * 2 + wcol] = sm;
    }
    __syncthreads();   // sync2 (sum exchange; also: all QK kl reads done)

    float inv4[4];
#pragma unroll
    for (int j = 0; j < 4; ++j) {
        const int qq = rbase + (g << 2) + j;
        float2 rr2 = *(const float2*)&reds[qq * 2];
        inv4[j] = 1.0f / (rr2.x + rr2.y + 1e-37f);
    }

    // ---- write P (bf16, UNNORMALIZED): 8B per tile per lane ----
    char* plw = smem + w * 4352;   // [16 q][272B]
#pragma unroll
    for (int tile = 0; tile < 8; ++tile) {
        uint2 pw2 = make_uint2(cvt_pk_bf16(acc[tile][0], acc[tile][1]),
                               cvt_pk_bf16(acc[tile][2], acc[tile][3]));
        *(uint2*)(plw + l15 * 272 + tile * 32 + g * 8) = pw2;
    }

    // ---- PV ----
    f32x4 o0 = zz, o1 = zz;
#pragma unroll
    for (int ks = 0; ks < 4; ++ks) {
        const short8v pa  = *(const short8v*)(plw + l15 * 272 + (ks * 32 + g * 8) * 2);
        const short8v vb0 = *(const short8v*)(smem + 34816 + l15 * 528        + (cb + ks * 32 + g * 8) * 2);
        const short8v vb1 = *(const short8v*)(smem + 34816 + (16 + l15) * 528 + (cb + ks * 32 + g * 8) * 2);
        o0 = __builtin_amdgcn_mfma_f32_16x16x32_bf16(pa, vb0, o0, 0, 0, 0);
        o1 = __builtin_amdgcn_mfma_f32_16x16x32_bf16(pa, vb1, o1, 0, 0, 0);
    }
    __syncthreads();   // sync3

    // ---- cross-half reduce + normalize-on-output + store ----
    float* ob = (float*)smem;   // [64][33] f32
    if (wcol == 1) {
#pragma unroll
        for (int j = 0; j < 4; ++j) {
            const int q = rbase + g * 4 + j;
            ob[q * 33 + l15]      = o0[j];
            ob[q * 33 + 16 + l15] = o1[j];
        }
    }
    __syncthreads();   // sync4
    if (wcol == 0) {
#pragma unroll
        for (int j = 0; j < 4; ++j) {
            const int q = rbase + g * 4 + j;
            float v0 = (o0[j] + ob[q * 33 + l15])      * inv4[j];
            float v1 = (o1[j] + ob[q * 33 + 16 + l15]) * inv4[j];
            attn[((size_t)bg * 64 + q) * 192 + h * 32 + l15]      = v0;
            attn[((size_t)bg * 64 + q) * 192 + h * 32 + 16 + l15] = v1;
        }
    }
}

// ---------------------------------------------------------------------------
// Kernel 4 (MFMA): final projection, swapped operands, direct stores.
// ---------------------------------------------------------------------------
__global__ __launch_bounds__(256, 4)
void k_oprojm(const float* __restrict__ attn, const __hip_bfloat16* __restrict__ wpb,
              const float* __restrict__ bp, float* __restrict__ out)
{
    __shared__ __align__(16) char smem[25600];   // at [64r][400B] bf16
    const int bid0 = blockIdx.x;
    const int bid = (bid0 & 7) * 384 + (bid0 >> 3);   // 3072 = 8 x 384, bijective
    const int oct = bid % 3;
    const int rt  = bid / 3;
    const int row0 = rt * 64;
    const int t = threadIdx.x;

    // ---- stage A: attn[row0..+64][192] f32 -> bf16 LDS (coalesced) ----
#pragma unroll
    for (int e0 = 0; e0 < 12; ++e0) {
        const int e = e0 * 256 + t;          // 3072 float4s
        const int r = e / 48, c4 = e % 48;
        float4 v = *(const float4*)(attn + (size_t)(row0 + r) * 192 + c4 * 4);
        uint2 pk = make_uint2(cvt_pk_bf16(v.x, v.y), cvt_pk_bf16(v.z, v.w));
        *(uint2*)(smem + r * 400 + c4 * 8) = pk;
    }
    __syncthreads();   // the ONLY barrier

    const int w = t >> 6, lane = t & 63;
    const int l15 = lane & 15, g = lane >> 4;
    const int mb = (w & 1) * 32;     // row quadrant
    const int nb = (w >> 1) * 32;    // oc quadrant

    const f32x4 zz = {0.0f, 0.0f, 0.0f, 0.0f};
    f32x4 acc00 = zz, acc01 = zz, acc10 = zz, acc11 = zz;
    const __hip_bfloat16* w0 = wpb + (size_t)(oct * 64 + nb + l15) * C_;
    const __hip_bfloat16* w1 = w0 + 16 * C_;
#pragma unroll
    for (int ks = 0; ks < 6; ++ks) {
        const short8v a0 = *(const short8v*)(smem + (mb + l15) * 400      + ks * 64 + g * 16);
        const short8v a1 = *(const short8v*)(smem + (mb + 16 + l15) * 400 + ks * 64 + g * 16);
        const short8v b0 = *(const short8v*)(w0 + ks * 32 + g * 8);
        const short8v b1 = *(const short8v*)(w1 + ks * 32 + g * 8);
        acc00 = __builtin_amdgcn_mfma_f32_16x16x32_bf16(b0, a0, acc00, 0, 0, 0);
        acc01 = __builtin_amdgcn_mfma_f32_16x16x32_bf16(b0, a1, acc01, 0, 0, 0);
        acc10 = __builtin_amdgcn_mfma_f32_16x16x32_bf16(b1, a0, acc10, 0, 0, 0);
        acc11 = __builtin_amdgcn_mfma_f32_16x16x32_bf16(b1, a1, acc11, 0, 0, 0);
    }

    const float4 bv0 = *(const float4*)(bp + oct * 64 + nb + g * 4);
    const float4 bv1 = *(const float4*)(bp + oct * 64 + nb + 16 + g * 4);
    float* d00 = out + (size_t)(row0 + mb + l15) * 192 + oct * 64 + nb + g * 4;
    float* d01 = out + (size_t)(row0 + mb + 16 + l15) * 192 + oct * 64 + nb + g * 4;
    float4 v;
    v = make_float4(acc00[0] + bv0.x, acc00[1] + bv0.y, acc00[2] + bv0.z, acc00[3] + bv0.w);
    *(float4*)d00 = v;
    v = make_float4(acc10[0] + bv1.x, acc10[1] + bv1.y, acc10[2] + bv1.z, acc10[3] + bv1.w);
    *(float4*)(d00 + 16) = v;
    v = make_float4(acc01[0] + bv0.x, acc01[1] + bv0.y, acc01[2] + bv0.z, acc01[3] + bv0.w);
    *(float4*)d01 = v;
    v = make_float4(acc11[0] + bv1.x, acc11[1] + bv1.y, acc11[2] + bv1.z, acc11[3] + bv1.w);
    *(float4*)(d01 + 16) = v;
}

// ---------------------------------------------------------------------------
extern "C" void kernel_launch(void* const* d_in, const int* in_sizes, int n_in,
                              void* d_out, int out_size, void* d_ws, size_t ws_size,
                              hipStream_t stream)
{
    (void)in_sizes; (void)n_in; (void)out_size; (void)ws_size;
    const float* x   = (const float*)d_in[0];
    const int* grph  = (const int*)d_in[1];     // jnp bool -> int32 per harness
    const float* wg  = (const float*)d_in[2];
    const float* bgb = (const float*)d_in[3];
    const float* wsm = (const float*)d_in[4];
    const float* bsm = (const float*)d_in[5];
    const float* wp  = (const float*)d_in[6];
    const float* bp  = (const float*)d_in[7];
    float* out = (float*)d_out;

    char* wsb = (char*)d_ws;
    __hip_bfloat16* xsk = (__hip_bfloat16*)wsb;                  // 25,165,824 B (K token-major, normalized)
    __hip_bfloat16* xsv = (__hip_bfloat16*)(wsb + 25165824ull);  // 25,165,824 B (V channel-major)
    __hip_bfloat16* qbf = (__hip_bfloat16*)(wsb + 50331648ull);  // 25,165,824 B (q bf16)
    float2* tbl = (float2*)(wsb + 75497472ull);                  // 32,768 B (rope table)
    unsigned int* gbits = (unsigned int*)(wsb + 75530240ull);    // 2,097,152 B (graph bits)
    __hip_bfloat16* wb  = (__hip_bfloat16*)(wsb + 77627392ull);  // 221,184 B (ws+wg bf16)
    __hip_bfloat16* wpb = wb + 110592;                           // 73,728 B (wp bf16)

    hipLaunchKernelGGL(k_prep,   dim3(2208), dim3(256), 0, stream,
                       grph, gbits, tbl, wsm, wg, wp, wb);
    hipLaunchKernelGGL(k_convm,  dim3(1024), dim3(256), 0, stream,
                       x, wb, bsm, bgb, tbl, xsk, xsv, qbf);
    hipLaunchKernelGGL(k_attn,   dim3(6144), dim3(512), 0, stream,
                       xsk, xsv, gbits, qbf, tbl, out);
    hipLaunchKernelGGL(k_oprojm, dim3(3072), dim3(256), 0, stream,
                       out, wpb, bp, out);
}